// Round 1
// baseline (391.975 us; speedup 1.0000x reference)
//
#include <hip/hip_runtime.h>
#include <hip/hip_bf16.h>
#include <cstdint>

// Problem constants
#define BATCH   16384
#define HDIM    2048
#define HHDIM   1024
#define PDIM    256
#define KNEG    64
#define NBUF    2000
#define M1      (2 * BATCH)          // 32768 rows through the projection head

typedef float  f32x4  __attribute__((ext_vector_type(4)));
typedef __bf16 bf16x8 __attribute__((ext_vector_type(8)));

typedef __attribute__((address_space(3))) unsigned int       lds_u32;
typedef __attribute__((address_space(1))) const unsigned int glb_u32;

__device__ __forceinline__ void gload_lds16(const void* g, void* l) {
  // async global->LDS, 16B per lane; LDS dest must be wave-uniform base (+lane*16 implicit)
  __builtin_amdgcn_global_load_lds((glb_u32*)g, (lds_u32*)l, 16, 0, 0);
}

__device__ __forceinline__ float dot4(f32x4 a, f32x4 b) {
  return a[0]*b[0] + a[1]*b[1] + a[2]*b[2] + a[3]*b[3];
}

// ---------------------------------------------------------------------------
// Transpose + cast: src [K][N] f32 row-major  ->  dst [N][K] bf16 row-major
// ---------------------------------------------------------------------------
__global__ void transpose_cast_kernel(const float* __restrict__ src,
                                      __bf16* __restrict__ dst, int K, int N) {
  __shared__ float tile[32][33];
  int bn = blockIdx.x * 32, bk = blockIdx.y * 32;
  int tx = threadIdx.x, ty = threadIdx.y;  // 32 x 8
  for (int j = 0; j < 32; j += 8)
    tile[ty + j][tx] = src[(size_t)(bk + ty + j) * N + bn + tx];
  __syncthreads();
  for (int j = 0; j < 32; j += 8)
    dst[(size_t)(bn + ty + j) * K + bk + tx] = (__bf16)tile[tx][ty + j];
}

// ---------------------------------------------------------------------------
// 128x128 tile MFMA GEMM, BK=32, 4 waves (2x2), 16x16x32 bf16 fragments.
//   C = A @ Bt^T (+bias) ; A: [M][KD]  (f32 reg-staged, or bf16 via gload_lds)
//   Bt: [N][KD] bf16 (pre-transposed weights)
//   AF32: A is fp32 split across two input pointers (anchors/positives)
//   RELU_OUT: relu + bf16 store, else plain f32 store
// ---------------------------------------------------------------------------
template <int KD, int NB, bool AF32, bool RELU_OUT>
__global__ __launch_bounds__(256)
void gemm_mfma(const void* __restrict__ A0v, const void* __restrict__ A1v,
               const __bf16* __restrict__ Bt, const float* __restrict__ bias,
               void* __restrict__ Cv) {
  __shared__ __bf16 lA[128 * 32];
  __shared__ __bf16 lB[128 * 32];

  const int nwg = 256 * NB / (AF32 ? 1 : 1) * (AF32 ? 1 : 1); (void)nwg;
  const int total_wg = (M1 / 128) * NB;
  int bid = blockIdx.x;
  const int q = total_wg >> 3;                 // divisible by 8 for our grids
  int swz = (bid & 7) * q + (bid >> 3);        // XCD-bijective swizzle
  const int mb = swz / NB, nb = swz % NB;
  const int mrow0 = mb * 128, ncol0 = nb * 128;
  const int NDIM = NB * 128;

  const int tid = threadIdx.x;
  const int wid = tid >> 6, lane = tid & 63;
  const int wr = wid >> 1, wc = wid & 1;
  const int fl = lane & 15, fh = lane >> 4;

  const float*  Af = nullptr;
  const __bf16* Ab = nullptr;
  if constexpr (AF32) {
    const float* A0 = (const float*)A0v;
    const float* A1 = (const float*)A1v;
    Af = (mrow0 < BATCH) ? (A0 + (size_t)mrow0 * KD)
                         : (A1 + (size_t)(mrow0 - BATCH) * KD);
  } else {
    Ab = (const __bf16*)A0v + (size_t)mrow0 * KD;
  }

  f32x4 acc[4][4] = {};

  // staging decomposition
  const int a_row = wid * 32 + (lane >> 2);    // +16 for round 1 (AF32 path)
  const int a_slot = lane & 3;

  const int KT = KD / 32;
  for (int kt = 0; kt < KT; ++kt) {
    f32x4 av[2][2];
    if constexpr (AF32) {
      const float* ap = Af + (size_t)a_row * KD + kt * 32 + a_slot * 8;
      av[0][0] = *(const f32x4*)(ap);
      av[0][1] = *(const f32x4*)(ap + 4);
      av[1][0] = *(const f32x4*)(ap + (size_t)16 * KD);
      av[1][1] = *(const f32x4*)(ap + (size_t)16 * KD + 4);
    }
    __syncthreads();  // previous tile's LDS reads complete

    // B tile: 8 chunks of 1KB; chunk rows 16c..16c+15; lane i: row=16c+i/4, slot=i%4
    {
      int chunk = wid * 2;
      for (int c = 0; c < 2; ++c, ++chunk) {
        int row = chunk * 16 + (lane >> 2);
        int sslot = (lane & 3) ^ (row & 3);    // pre-swizzled source -> linear LDS
        const __bf16* srcp = Bt + (size_t)(ncol0 + row) * KD + kt * 32 + sslot * 8;
        gload_lds16(srcp, (void*)(lB + chunk * 512));
      }
    }
    if constexpr (AF32) {
      for (int r = 0; r < 2; ++r) {
        int row = a_row + r * 16;
        int sslot = a_slot ^ (row & 3);
        bf16x8 w;
        for (int j = 0; j < 4; ++j) {
          w[j]     = (__bf16)av[r][0][j];
          w[4 + j] = (__bf16)av[r][1][j];
        }
        *(bf16x8*)(lA + row * 32 + sslot * 8) = w;
      }
    } else {
      int chunk = wid * 2;
      for (int c = 0; c < 2; ++c, ++chunk) {
        int row = chunk * 16 + (lane >> 2);
        int sslot = (lane & 3) ^ (row & 3);
        const __bf16* srcp = Ab + (size_t)row * KD + kt * 32 + sslot * 8;
        gload_lds16(srcp, (void*)(lA + chunk * 512));
      }
    }
    __syncthreads();  // drains vmcnt (gload_lds) + lgkm (ds_write)

    bf16x8 afr[4], bfr[4];
    for (int mi = 0; mi < 4; ++mi) {
      int row = wr * 64 + mi * 16 + fl;
      int sslot = fh ^ (row & 3);
      afr[mi] = *(const bf16x8*)(lA + row * 32 + sslot * 8);
    }
    for (int ni = 0; ni < 4; ++ni) {
      int row = wc * 64 + ni * 16 + fl;
      int sslot = fh ^ (row & 3);
      bfr[ni] = *(const bf16x8*)(lB + row * 32 + sslot * 8);
    }
    for (int mi = 0; mi < 4; ++mi)
      for (int ni = 0; ni < 4; ++ni)
        acc[mi][ni] = __builtin_amdgcn_mfma_f32_16x16x32_bf16(
            afr[mi], bfr[ni], acc[mi][ni], 0, 0, 0);
  }

  // epilogue: bias (+relu/cast)
  for (int ni = 0; ni < 4; ++ni) {
    int col = ncol0 + wc * 64 + ni * 16 + fl;
    float bv = bias[col];
    for (int mi = 0; mi < 4; ++mi) {
      for (int r = 0; r < 4; ++r) {
        size_t row = (size_t)mrow0 + wr * 64 + mi * 16 + fh * 4 + r;
        float v = acc[mi][ni][r] + bv;
        if constexpr (RELU_OUT) {
          v = fmaxf(v, 0.0f);
          ((__bf16*)Cv)[row * NDIM + col] = (__bf16)v;
        } else {
          ((float*)Cv)[row * NDIM + col] = v;
        }
      }
    }
  }
}

// ---------------------------------------------------------------------------
// LayerNorm + L2 normalize, in place on X [M1][256] f32. One wave per row.
// ---------------------------------------------------------------------------
__global__ __launch_bounds__(256)
void ln_l2_kernel(float* __restrict__ X, const float* __restrict__ g,
                  const float* __restrict__ be) {
  int row  = blockIdx.x * 4 + (threadIdx.x >> 6);
  int lane = threadIdx.x & 63;
  float* xp = X + (size_t)row * PDIM + lane * 4;
  f32x4 v = *(const f32x4*)xp;

  float s = v[0] + v[1] + v[2] + v[3];
  for (int m = 1; m < 64; m <<= 1) s += __shfl_xor(s, m, 64);
  float mu = s * (1.0f / PDIM);

  f32x4 d;
  for (int j = 0; j < 4; ++j) d[j] = v[j] - mu;
  float qv = dot4(d, d);
  for (int m = 1; m < 64; m <<= 1) qv += __shfl_xor(qv, m, 64);
  float rs = rsqrtf(qv * (1.0f / PDIM) + 1e-5f);

  f32x4 g4 = *(const f32x4*)(g + lane * 4);
  f32x4 b4 = *(const f32x4*)(be + lane * 4);
  f32x4 y;
  for (int j = 0; j < 4; ++j) y[j] = d[j] * rs * g4[j] + b4[j];

  float n2 = dot4(y, y);
  for (int m = 1; m < 64; m <<= 1) n2 += __shfl_xor(n2, m, 64);
  float sc = 1.0f / fmaxf(sqrtf(n2), 1e-12f);
  for (int j = 0; j < 4; ++j) y[j] *= sc;
  *(f32x4*)xp = y;
}

// ---------------------------------------------------------------------------
// Per-row contrastive loss. One wave per row; 16-lane groups handle 4 negs
// at a time; each lane ends holding one neg logit; butterfly softmax.
// ---------------------------------------------------------------------------
__global__ __launch_bounds__(256)
void loss_kernel(const float* __restrict__ X, const float* __restrict__ negbuf,
                 const int* __restrict__ nidx, float* __restrict__ partials) {
  __shared__ float lsum[4];
  int b    = blockIdx.x * 4 + (threadIdx.x >> 6);
  int lane = threadIdx.x & 63;
  int g = lane >> 4, lg = lane & 15;

  const float* arow = X + (size_t)b * PDIM;
  const float* prow = X + (size_t)(BATCH + b) * PDIM;

  f32x4 a4[4];
  for (int j = 0; j < 4; ++j) a4[j] = *(const f32x4*)(arow + lg * 16 + j * 4);

  float ps = 0.0f;
  for (int j = 0; j < 4; ++j) {
    f32x4 p = *(const f32x4*)(prow + lg * 16 + j * 4);
    ps += dot4(a4[j], p);
  }
  for (int m = 1; m < 16; m <<= 1) ps += __shfl_xor(ps, m, 64);
  float pos = ps * 2.0f;  // /TEMPERATURE

  float myneg = -3.0e38f;
  for (int k4 = 0; k4 < 16; ++k4) {
    int k = k4 * 4 + g;
    int idx = nidx[(size_t)b * KNEG + k];
    const float* nrow = negbuf + (size_t)idx * PDIM;
    float sv = 0.0f;
    for (int j = 0; j < 4; ++j) {
      f32x4 nv = *(const f32x4*)(nrow + lg * 16 + j * 4);
      sv += dot4(a4[j], nv);
    }
    for (int m = 1; m < 16; m <<= 1) sv += __shfl_xor(sv, m, 64);
    if (lg == k4) myneg = sv * 2.0f;
  }

  float mx = myneg;
  for (int m = 1; m < 64; m <<= 1) mx = fmaxf(mx, __shfl_xor(mx, m, 64));
  mx = fmaxf(mx, pos);
  float e = expf(myneg - mx);
  for (int m = 1; m < 64; m <<= 1) e += __shfl_xor(e, m, 64);
  float tot = e + expf(pos - mx);
  float lb = -(pos - mx - logf(tot));

  if (lane == 0) lsum[threadIdx.x >> 6] = lb;
  __syncthreads();
  if (threadIdx.x == 0)
    partials[blockIdx.x] = lsum[0] + lsum[1] + lsum[2] + lsum[3];
}

__global__ void finalize_kernel(const float* __restrict__ partials,
                                float* __restrict__ out) {
  __shared__ float ls[4];
  int tid = threadIdx.x;
  float s = 0.0f;
  for (int i = tid; i < 4096; i += 256) s += partials[i];
  for (int m = 1; m < 64; m <<= 1) s += __shfl_xor(s, m, 64);
  if ((tid & 63) == 0) ls[tid >> 6] = s;
  __syncthreads();
  if (tid == 0) out[0] = (ls[0] + ls[1] + ls[2] + ls[3]) * (1.0f / BATCH);
}

// ---------------------------------------------------------------------------
extern "C" void kernel_launch(void* const* d_in, const int* in_sizes, int n_in,
                              void* d_out, int out_size, void* d_ws, size_t ws_size,
                              hipStream_t stream) {
  const float* hidden   = (const float*)d_in[0];
  const float* positive = (const float*)d_in[1];
  const float* negbuf   = (const float*)d_in[2];
  const float* W1       = (const float*)d_in[3];
  const float* b1       = (const float*)d_in[4];
  const float* W2       = (const float*)d_in[5];
  const float* b2       = (const float*)d_in[6];
  const float* gamma    = (const float*)d_in[7];
  const float* beta     = (const float*)d_in[8];
  const int*   nidx     = (const int*)d_in[9];
  float* out = (float*)d_out;

  char* ws = (char*)d_ws;
  __bf16* W1T      = (__bf16*)(ws);                       //  4 MiB [1024][2048]
  __bf16* W2T      = (__bf16*)(ws + 4194304);             //  0.5 MiB [256][1024]
  __bf16* Y1       = (__bf16*)(ws + 4718592);             // 64 MiB [32768][1024]
  float*  X        = (float*) (ws + 71827456);            // 32 MiB [32768][256]
  float*  partials = (float*) (ws + 105381888);           // 16 KiB [4096]

  // W transposes + bf16 cast
  transpose_cast_kernel<<<dim3(HHDIM / 32, HDIM / 32), dim3(32, 8), 0, stream>>>(
      W1, W1T, HDIM, HHDIM);
  transpose_cast_kernel<<<dim3(PDIM / 32, HHDIM / 32), dim3(32, 8), 0, stream>>>(
      W2, W2T, HHDIM, PDIM);

  // GEMM1: [32768,2048] @ [2048,1024] + b1, relu -> Y1 (bf16)
  gemm_mfma<HDIM, HHDIM / 128, true, true>
      <<<(M1 / 128) * (HHDIM / 128), 256, 0, stream>>>(
          hidden, positive, W1T, b1, Y1);

  // GEMM2: [32768,1024] @ [1024,256] + b2 -> X (f32)
  gemm_mfma<HHDIM, PDIM / 128, false, false>
      <<<(M1 / 128) * (PDIM / 128), 256, 0, stream>>>(
          Y1, nullptr, W2T, b2, X);

  // LayerNorm + L2 normalize (in place)
  ln_l2_kernel<<<M1 / 4, 256, 0, stream>>>(X, gamma, beta);

  // Per-row loss partials, then reduce
  loss_kernel<<<BATCH / 4 / 4 * 4, 256, 0, stream>>>(X, negbuf, nidx, partials);
  finalize_kernel<<<1, 256, 0, stream>>>(partials, out);
}

// Round 2
// 380.086 us; speedup vs baseline: 1.0313x; 1.0313x over previous
//
#include <hip/hip_runtime.h>
#include <hip/hip_bf16.h>
#include <cstdint>

// Problem constants
#define BATCH   16384
#define HDIM    2048
#define HHDIM   1024
#define PDIM    256
#define KNEG    64
#define NBUF    2000
#define M1      (2 * BATCH)          // 32768 rows through the projection head

typedef float  f32x4  __attribute__((ext_vector_type(4)));
typedef __bf16 bf16x8 __attribute__((ext_vector_type(8)));

typedef __attribute__((address_space(3))) unsigned int       lds_u32;
typedef __attribute__((address_space(1))) const unsigned int glb_u32;

__device__ __forceinline__ void gload_lds16(const void* g, void* l) {
  // async global->LDS, 16B per lane; LDS dest is wave-uniform base (+lane*16 implicit)
  __builtin_amdgcn_global_load_lds((glb_u32*)g, (lds_u32*)l, 16, 0, 0);
}

__device__ __forceinline__ float dot4(f32x4 a, f32x4 b) {
  return a[0]*b[0] + a[1]*b[1] + a[2]*b[2] + a[3]*b[3];
}

// LDS slot swizzle: row stride is 64B (4 slots of 16B); banks repeat every 2
// rows, so XOR the slot with (row>>1)&3 -> within any 16 consecutive rows each
// 16B-slot-position mod 128B is hit exactly twice (2 lanes/bank = free).
__device__ __forceinline__ int swz(int row) { return (row >> 1) & 3; }

// ---------------------------------------------------------------------------
// f32 -> bf16 cast, 8 elems/thread, grid-stride
// ---------------------------------------------------------------------------
__global__ __launch_bounds__(256)
void cast_bf16_kernel(const float* __restrict__ src, __bf16* __restrict__ dst,
                      long n8) {
  long i = (long)blockIdx.x * blockDim.x + threadIdx.x;
  long stride = (long)gridDim.x * blockDim.x;
  for (; i < n8; i += stride) {
    f32x4 a = ((const f32x4*)src)[2 * i];
    f32x4 b = ((const f32x4*)src)[2 * i + 1];
    bf16x8 w;
    for (int j = 0; j < 4; ++j) { w[j] = (__bf16)a[j]; w[4 + j] = (__bf16)b[j]; }
    ((bf16x8*)dst)[i] = w;
  }
}

// ---------------------------------------------------------------------------
// Transpose + cast: src [K][N] f32 row-major  ->  dst [N][K] bf16 row-major
// ---------------------------------------------------------------------------
__global__ void transpose_cast_kernel(const float* __restrict__ src,
                                      __bf16* __restrict__ dst, int K, int N) {
  __shared__ float tile[32][33];
  int bn = blockIdx.x * 32, bk = blockIdx.y * 32;
  int tx = threadIdx.x, ty = threadIdx.y;  // 32 x 8
  for (int j = 0; j < 32; j += 8)
    tile[ty + j][tx] = src[(size_t)(bk + ty + j) * N + bn + tx];
  __syncthreads();
  for (int j = 0; j < 32; j += 8)
    dst[(size_t)(bn + ty + j) * K + bk + tx] = (__bf16)tile[tx][ty + j];
}

// ---------------------------------------------------------------------------
// 128x128 tile MFMA GEMM, BK=32, 4 waves (2x2), 16x16x32 bf16 fragments.
//   C = A @ Bt^T (+bias) ; A: bf16 [M][KD] via gload_lds, or f32 reg-staged
//   Bt: [N][KD] bf16 (pre-transposed weights)
//   AF32: A is fp32 split across two input pointers (anchors/positives)
//   RELU_OUT: relu + bf16 store, else plain f32 store
// ---------------------------------------------------------------------------
template <int KD, int NB, bool AF32, bool RELU_OUT>
__global__ __launch_bounds__(256)
void gemm_mfma(const void* __restrict__ A0v, const void* __restrict__ A1v,
               const __bf16* __restrict__ Bt, const float* __restrict__ bias,
               void* __restrict__ Cv) {
  __shared__ __bf16 lA[128 * 32];
  __shared__ __bf16 lB[128 * 32];

  const int total_wg = (M1 / 128) * NB;
  int bid = blockIdx.x;
  const int q = total_wg >> 3;                 // divisible by 8 for our grids
  int swzb = (bid & 7) * q + (bid >> 3);       // XCD-bijective swizzle
  const int mb = swzb / NB, nb = swzb % NB;
  const int mrow0 = mb * 128, ncol0 = nb * 128;
  const int NDIM = NB * 128;

  const int tid = threadIdx.x;
  const int wid = tid >> 6, lane = tid & 63;
  const int wr = wid >> 1, wc = wid & 1;
  const int fl = lane & 15, fh = lane >> 4;

  const float*  Af = nullptr;
  const __bf16* Ab = nullptr;
  if constexpr (AF32) {
    const float* A0 = (const float*)A0v;
    const float* A1 = (const float*)A1v;
    Af = (mrow0 < BATCH) ? (A0 + (size_t)mrow0 * KD)
                         : (A1 + (size_t)(mrow0 - BATCH) * KD);
  } else {
    Ab = (const __bf16*)A0v + (size_t)mrow0 * KD;
  }

  f32x4 acc[4][4] = {};

  const int a_row  = wid * 32 + (lane >> 2);   // AF32 staging decomposition
  const int a_slot = lane & 3;

  const int KT = KD / 32;
  for (int kt = 0; kt < KT; ++kt) {
    f32x4 av[2][2];
    if constexpr (AF32) {
      const float* ap = Af + (size_t)a_row * KD + kt * 32 + a_slot * 8;
      av[0][0] = *(const f32x4*)(ap);
      av[0][1] = *(const f32x4*)(ap + 4);
      av[1][0] = *(const f32x4*)(ap + (size_t)16 * KD);
      av[1][1] = *(const f32x4*)(ap + (size_t)16 * KD + 4);
    }
    __syncthreads();  // previous tile's LDS reads complete

    // B tile: 8 chunks of 1KB; chunk rows 16c..16c+15; lane i: row=16c+i/4
    {
      int chunk = wid * 2;
      for (int c = 0; c < 2; ++c, ++chunk) {
        int row = chunk * 16 + (lane >> 2);
        int sslot = (lane & 3) ^ swz(row);     // pre-swizzled source -> linear LDS
        const __bf16* srcp = Bt + (size_t)(ncol0 + row) * KD + kt * 32 + sslot * 8;
        gload_lds16(srcp, (void*)(lB + chunk * 512));
      }
    }
    if constexpr (AF32) {
      for (int r = 0; r < 2; ++r) {
        int row = a_row + r * 16;
        int sslot = a_slot ^ swz(row);
        bf16x8 w;
        for (int j = 0; j < 4; ++j) {
          w[j]     = (__bf16)av[r][0][j];
          w[4 + j] = (__bf16)av[r][1][j];
        }
        *(bf16x8*)(lA + row * 32 + sslot * 8) = w;
      }
    } else {
      int chunk = wid * 2;
      for (int c = 0; c < 2; ++c, ++chunk) {
        int row = chunk * 16 + (lane >> 2);
        int sslot = (lane & 3) ^ swz(row);
        const __bf16* srcp = Ab + (size_t)row * KD + kt * 32 + sslot * 8;
        gload_lds16(srcp, (void*)(lA + chunk * 512));
      }
    }
    __syncthreads();  // drains vmcnt (gload_lds) + lgkm (ds_write)

    bf16x8 afr[4], bfr[4];
    for (int mi = 0; mi < 4; ++mi) {
      int row = wr * 64 + mi * 16 + fl;
      afr[mi] = *(const bf16x8*)(lA + row * 32 + (fh ^ swz(row)) * 8);
    }
    for (int ni = 0; ni < 4; ++ni) {
      int row = wc * 64 + ni * 16 + fl;
      bfr[ni] = *(const bf16x8*)(lB + row * 32 + (fh ^ swz(row)) * 8);
    }
    for (int mi = 0; mi < 4; ++mi)
      for (int ni = 0; ni < 4; ++ni)
        acc[mi][ni] = __builtin_amdgcn_mfma_f32_16x16x32_bf16(
            afr[mi], bfr[ni], acc[mi][ni], 0, 0, 0);
  }

  // epilogue: bias (+relu/cast)
  for (int ni = 0; ni < 4; ++ni) {
    int col = ncol0 + wc * 64 + ni * 16 + fl;
    float bv = bias[col];
    for (int mi = 0; mi < 4; ++mi) {
      for (int r = 0; r < 4; ++r) {
        size_t row = (size_t)mrow0 + wr * 64 + mi * 16 + fh * 4 + r;
        float v = acc[mi][ni][r] + bv;
        if constexpr (RELU_OUT) {
          v = fmaxf(v, 0.0f);
          ((__bf16*)Cv)[row * NDIM + col] = (__bf16)v;
        } else {
          ((float*)Cv)[row * NDIM + col] = v;
        }
      }
    }
  }
}

// ---------------------------------------------------------------------------
// LayerNorm + L2 normalize, in place on X [M1][256] f32. One wave per row.
// ---------------------------------------------------------------------------
__global__ __launch_bounds__(256)
void ln_l2_kernel(float* __restrict__ X, const float* __restrict__ g,
                  const float* __restrict__ be) {
  int row  = blockIdx.x * 4 + (threadIdx.x >> 6);
  int lane = threadIdx.x & 63;
  float* xp = X + (size_t)row * PDIM + lane * 4;
  f32x4 v = *(const f32x4*)xp;

  float s = v[0] + v[1] + v[2] + v[3];
  for (int m = 1; m < 64; m <<= 1) s += __shfl_xor(s, m, 64);
  float mu = s * (1.0f / PDIM);

  f32x4 d;
  for (int j = 0; j < 4; ++j) d[j] = v[j] - mu;
  float qv = dot4(d, d);
  for (int m = 1; m < 64; m <<= 1) qv += __shfl_xor(qv, m, 64);
  float rs = rsqrtf(qv * (1.0f / PDIM) + 1e-5f);

  f32x4 g4 = *(const f32x4*)(g + lane * 4);
  f32x4 b4 = *(const f32x4*)(be + lane * 4);
  f32x4 y;
  for (int j = 0; j < 4; ++j) y[j] = d[j] * rs * g4[j] + b4[j];

  float n2 = dot4(y, y);
  for (int m = 1; m < 64; m <<= 1) n2 += __shfl_xor(n2, m, 64);
  float sc = 1.0f / fmaxf(sqrtf(n2), 1e-12f);
  for (int j = 0; j < 4; ++j) y[j] *= sc;
  *(f32x4*)xp = y;
}

// ---------------------------------------------------------------------------
// Per-row contrastive loss. One wave per row; 16-lane groups handle 4 negs
// at a time; each lane ends holding one neg logit; butterfly softmax.
// ---------------------------------------------------------------------------
__global__ __launch_bounds__(256)
void loss_kernel(const float* __restrict__ X, const float* __restrict__ negbuf,
                 const int* __restrict__ nidx, float* __restrict__ partials) {
  __shared__ float lsum[4];
  int b    = blockIdx.x * 4 + (threadIdx.x >> 6);
  int lane = threadIdx.x & 63;
  int g = lane >> 4, lg = lane & 15;

  const float* arow = X + (size_t)b * PDIM;
  const float* prow = X + (size_t)(BATCH + b) * PDIM;

  f32x4 a4[4];
  for (int j = 0; j < 4; ++j) a4[j] = *(const f32x4*)(arow + lg * 16 + j * 4);

  float ps = 0.0f;
  for (int j = 0; j < 4; ++j) {
    f32x4 p = *(const f32x4*)(prow + lg * 16 + j * 4);
    ps += dot4(a4[j], p);
  }
  for (int m = 1; m < 16; m <<= 1) ps += __shfl_xor(ps, m, 64);
  float pos = ps * 2.0f;  // /TEMPERATURE

  float myneg = -3.0e38f;
  for (int k4 = 0; k4 < 16; ++k4) {
    int k = k4 * 4 + g;
    int idx = nidx[(size_t)b * KNEG + k];
    const float* nrow = negbuf + (size_t)idx * PDIM;
    float sv = 0.0f;
    for (int j = 0; j < 4; ++j) {
      f32x4 nv = *(const f32x4*)(nrow + lg * 16 + j * 4);
      sv += dot4(a4[j], nv);
    }
    for (int m = 1; m < 16; m <<= 1) sv += __shfl_xor(sv, m, 64);
    if (lg == k4) myneg = sv * 2.0f;
  }

  float mx = myneg;
  for (int m = 1; m < 64; m <<= 1) mx = fmaxf(mx, __shfl_xor(mx, m, 64));
  mx = fmaxf(mx, pos);
  float e = expf(myneg - mx);
  for (int m = 1; m < 64; m <<= 1) e += __shfl_xor(e, m, 64);
  float tot = e + expf(pos - mx);
  float lb = -(pos - mx - logf(tot));

  if (lane == 0) lsum[threadIdx.x >> 6] = lb;
  __syncthreads();
  if (threadIdx.x == 0)
    partials[blockIdx.x] = lsum[0] + lsum[1] + lsum[2] + lsum[3];
}

__global__ void finalize_kernel(const float* __restrict__ partials,
                                float* __restrict__ out) {
  __shared__ float ls[4];
  int tid = threadIdx.x;
  float s = 0.0f;
  for (int i = tid; i < 4096; i += 256) s += partials[i];
  for (int m = 1; m < 64; m <<= 1) s += __shfl_xor(s, m, 64);
  if ((tid & 63) == 0) ls[tid >> 6] = s;
  __syncthreads();
  if (tid == 0) out[0] = (ls[0] + ls[1] + ls[2] + ls[3]) * (1.0f / BATCH);
}

// ---------------------------------------------------------------------------
extern "C" void kernel_launch(void* const* d_in, const int* in_sizes, int n_in,
                              void* d_out, int out_size, void* d_ws, size_t ws_size,
                              hipStream_t stream) {
  const float* hidden   = (const float*)d_in[0];
  const float* positive = (const float*)d_in[1];
  const float* negbuf   = (const float*)d_in[2];
  const float* W1       = (const float*)d_in[3];
  const float* b1       = (const float*)d_in[4];
  const float* W2       = (const float*)d_in[5];
  const float* b2       = (const float*)d_in[6];
  const float* gamma    = (const float*)d_in[7];
  const float* beta     = (const float*)d_in[8];
  const int*   nidx     = (const int*)d_in[9];
  float* out = (float*)d_out;

  char* ws = (char*)d_ws;

  // Big layout (bf16-A path), ~197 MiB:
  //   Abf [32768][2048] bf16 @ 0           (134 MiB)  -- dead after GEMM1
  //   Y1  [32768][1024] bf16 @ 134 MiB     ( 64 MiB)
  //   W1T                    @ 198 MiB     (  4 MiB)
  //   W2T                    @ 202 MiB     (0.5 MiB)
  //   partials               @ 202.5 MiB   ( 16 KiB)
  //   X   [32768][256] f32   @ 0 (overlaps dead Abf, 32 MiB)
  const size_t OFF_Y1   = 134217728;
  const size_t OFF_W1T  = OFF_Y1 + 67108864;
  const size_t OFF_W2T  = OFF_W1T + 4194304;
  const size_t OFF_PART = OFF_W2T + 524288;
  const size_t NEED_BIG = OFF_PART + 16384;

  const bool big = (ws_size >= NEED_BIG);

  __bf16* W1T; __bf16* W2T; __bf16* Y1; float* X; float* partials;
  __bf16* Abf = nullptr;
  if (big) {
    Abf      = (__bf16*)(ws);
    Y1       = (__bf16*)(ws + OFF_Y1);
    W1T      = (__bf16*)(ws + OFF_W1T);
    W2T      = (__bf16*)(ws + OFF_W2T);
    partials = (float*) (ws + OFF_PART);
    X        = (float*) (ws);  // overlaps dead Abf
  } else {
    // fallback layout (fp32 reg-staged A), ~100.5 MiB
    W1T      = (__bf16*)(ws);
    W2T      = (__bf16*)(ws + 4194304);
    Y1       = (__bf16*)(ws + 4718592);
    X        = (float*) (ws + 71827456);
    partials = (float*) (ws + 105381888);
  }

  // W transposes + bf16 cast
  transpose_cast_kernel<<<dim3(HHDIM / 32, HDIM / 32), dim3(32, 8), 0, stream>>>(
      W1, W1T, HDIM, HHDIM);
  transpose_cast_kernel<<<dim3(PDIM / 32, HHDIM / 32), dim3(32, 8), 0, stream>>>(
      W2, W2T, HHDIM, PDIM);

  if (big) {
    // cast anchors+positives to bf16 rows [0,16384) and [16384,32768)
    const long n8 = (long)BATCH * HDIM / 8;
    cast_bf16_kernel<<<2048, 256, 0, stream>>>(hidden, Abf, n8);
    cast_bf16_kernel<<<2048, 256, 0, stream>>>(positive, Abf + (size_t)BATCH * HDIM, n8);
    gemm_mfma<HDIM, HHDIM / 128, false, true>
        <<<(M1 / 128) * (HHDIM / 128), 256, 0, stream>>>(
            Abf, nullptr, W1T, b1, Y1);
  } else {
    gemm_mfma<HDIM, HHDIM / 128, true, true>
        <<<(M1 / 128) * (HHDIM / 128), 256, 0, stream>>>(
            hidden, positive, W1T, b1, Y1);
  }

  // GEMM2: [32768,1024] @ [1024,256] + b2 -> X (f32)
  gemm_mfma<HHDIM, PDIM / 128, false, false>
      <<<(M1 / 128) * (PDIM / 128), 256, 0, stream>>>(
          Y1, nullptr, W2T, b2, X);

  // LayerNorm + L2 normalize (in place)
  ln_l2_kernel<<<M1 / 4, 256, 0, stream>>>(X, gamma, beta);

  // Per-row loss partials, then reduce
  loss_kernel<<<BATCH / 4, 256, 0, stream>>>(X, negbuf, nidx, partials);
  finalize_kernel<<<1, 256, 0, stream>>>(partials, out);
}

// Round 3
// 357.971 us; speedup vs baseline: 1.0950x; 1.0618x over previous
//
#include <hip/hip_runtime.h>
#include <hip/hip_bf16.h>
#include <cstdint>

// Problem constants
#define BATCH   16384
#define HDIM    2048
#define HHDIM   1024
#define PDIM    256
#define KNEG    64
#define NBUF    2000
#define M1      (2 * BATCH)          // 32768 rows through the projection head

typedef float  f32x4  __attribute__((ext_vector_type(4)));
typedef __bf16 bf16x8 __attribute__((ext_vector_type(8)));

typedef __attribute__((address_space(3))) unsigned int       lds_u32;
typedef __attribute__((address_space(1))) const unsigned int glb_u32;

__device__ __forceinline__ void gload_lds16(const void* g, void* l) {
  __builtin_amdgcn_global_load_lds((glb_u32*)g, (lds_u32*)l, 16, 0, 0);
}

__device__ __forceinline__ float dot4(f32x4 a, f32x4 b) {
  return a[0]*b[0] + a[1]*b[1] + a[2]*b[2] + a[3]*b[3];
}

// LDS slot swizzle (BK=32: row = 64B = 4 slots of 16B; bank cycle = 2 rows):
// sslot = slot ^ ((row>>1)&3) -> 2 lanes/bank within each 16-lane phase = free.
// Verified 0 SQ_LDS_BANK_CONFLICT in round 2.
__device__ __forceinline__ int swz(int row) { return (row >> 1) & 3; }

#define VMCNT(n) asm volatile("s_waitcnt vmcnt(" #n ")" ::: "memory")

// ---------------------------------------------------------------------------
// f32 -> bf16 cast, 8 elems/thread, grid-stride
// ---------------------------------------------------------------------------
__global__ __launch_bounds__(256)
void cast_bf16_kernel(const float* __restrict__ src, __bf16* __restrict__ dst,
                      long n8) {
  long i = (long)blockIdx.x * blockDim.x + threadIdx.x;
  long stride = (long)gridDim.x * blockDim.x;
  for (; i < n8; i += stride) {
    f32x4 a = ((const f32x4*)src)[2 * i];
    f32x4 b = ((const f32x4*)src)[2 * i + 1];
    bf16x8 w;
    for (int j = 0; j < 4; ++j) { w[j] = (__bf16)a[j]; w[4 + j] = (__bf16)b[j]; }
    ((bf16x8*)dst)[i] = w;
  }
}

// ---------------------------------------------------------------------------
// Transpose + cast: src [K][N] f32 row-major  ->  dst [N][K] bf16 row-major
// ---------------------------------------------------------------------------
__global__ void transpose_cast_kernel(const float* __restrict__ src,
                                      __bf16* __restrict__ dst, int K, int N) {
  __shared__ float tile[32][33];
  int bn = blockIdx.x * 32, bk = blockIdx.y * 32;
  int tx = threadIdx.x, ty = threadIdx.y;  // 32 x 8
  for (int j = 0; j < 32; j += 8)
    tile[ty + j][tx] = src[(size_t)(bk + ty + j) * N + bn + tx];
  __syncthreads();
  for (int j = 0; j < 32; j += 8)
    dst[(size_t)(bn + ty + j) * K + bk + tx] = (__bf16)tile[tx][ty + j];
}

// ---------------------------------------------------------------------------
// Pipelined MFMA GEMM: C[M][NBt*256] = A[M][KD] @ Bt[NBt*256][KD]^T + bias
//  - 512 threads = 8 waves (2 x 4); per-wave output (BM/2) x 64
//  - BK=32, 3-deep LDS ring, counted vmcnt (T4), setprio (T5), raw barriers
//  - stages for tile t+2 issued during tile t; vmcnt(S) at tile end leaves
//    exactly t+2's S loads in flight ==> tile t+1 landed for all waves
// ---------------------------------------------------------------------------
template <int KD, int BM, int NBt, bool RELU_OUT, int GRID>
__global__ __launch_bounds__(512, 2)
void gemm_pipe(const __bf16* __restrict__ A, const __bf16* __restrict__ Bt,
               const float* __restrict__ bias, void* __restrict__ Cv) {
  constexpr int MI   = BM / 32;          // 16-row fragments per wave
  constexpr int KT   = KD / 32;          // K-tiles
  constexpr int S    = (BM == 256) ? 4 : 3;  // stage loads per tile per thread
  constexpr int ABUF = BM * 32;          // elements per A ring slot
  constexpr int BBUF = 256 * 32;
  constexpr int NDIM = NBt * 256;
  constexpr int nAch = (BM == 256) ? 2 : 1;  // A chunks per wave

  __shared__ __bf16 lA[3 * ABUF];
  __shared__ __bf16 lB[3 * BBUF];

  // XCD-bijective block swizzle (GRID divisible by 8)
  constexpr int Q = GRID / 8;
  int bid = blockIdx.x;
  int swb = (bid & 7) * Q + (bid >> 3);
  const int mb = swb / NBt, nb = swb % NBt;
  const long mrow0 = (long)mb * BM;
  const int  ncol0 = nb * 256;

  const int tid  = threadIdx.x;
  const int wid  = tid >> 6, lane = tid & 63;
  const int wr   = wid >> 2, wc   = wid & 3;   // 2 x 4 wave grid
  const int fl   = lane & 15, fh  = lane >> 4;

  // Fragment LDS element-offsets (ring-slot-relative, tile-invariant)
  int offA[MI];
  #pragma unroll
  for (int mi = 0; mi < MI; ++mi) {
    int row = wr * (BM / 2) + mi * 16 + fl;
    offA[mi] = row * 32 + ((fh ^ swz(row)) * 8);
  }
  int offB[4];
  #pragma unroll
  for (int ni = 0; ni < 4; ++ni) {
    int row = wc * 64 + ni * 16 + fl;
    offB[ni] = row * 32 + ((fh ^ swz(row)) * 8);
  }

  // Staging source offsets (pre-swizzled global source -> linear LDS dest)
  long aSrc[2]; int aDst[2];
  #pragma unroll
  for (int c = 0; c < nAch; ++c) {
    int chunk = (BM == 256) ? (wid * 2 + c) : wid;
    int row   = chunk * 16 + (lane >> 2);
    int slot  = (lane & 3) ^ swz(row);
    aSrc[c] = (mrow0 + row) * (long)KD + slot * 8;
    aDst[c] = chunk * 512;
  }
  long bSrc[2]; int bDst[2];
  #pragma unroll
  for (int c = 0; c < 2; ++c) {
    int chunk = wid * 2 + c;
    int row   = chunk * 16 + (lane >> 2);
    int slot  = (lane & 3) ^ swz(row);
    bSrc[c] = (long)(ncol0 + row) * KD + slot * 8;
    bDst[c] = chunk * 512;
  }

  auto stageA = [&](int kt, int bufi) {
    #pragma unroll
    for (int c = 0; c < nAch; ++c)
      gload_lds16(A + aSrc[c] + kt * 32, (void*)(lA + bufi * ABUF + aDst[c]));
  };
  auto stageB = [&](int kt, int bufi) {
    #pragma unroll
    for (int c = 0; c < 2; ++c)
      gload_lds16(Bt + bSrc[c] + kt * 32, (void*)(lB + bufi * BBUF + bDst[c]));
  };

  // Prologue: tiles 0 and 1 in flight; wait for tile 0 only.
  stageA(0, 0); stageB(0, 0);
  stageA(1, 1); stageB(1, 1);
  if constexpr (S == 4) VMCNT(4); else VMCNT(3);
  __builtin_amdgcn_s_barrier();
  __builtin_amdgcn_sched_barrier(0);

  f32x4 acc[MI][4] = {};

  int cur = 0;
  for (int t = 0; t < KT; ++t) {
    const int stg = (cur == 0) ? 2 : cur - 1;   // == (t+2)%3
    const __bf16* bufA = lA + cur * ABUF;
    const __bf16* bufB = lB + cur * BBUF;

    // ---- phase 0: A frags + B frags {0,1}; stage A(t+2); MFMA half 1
    bf16x8 af[MI];
    #pragma unroll
    for (int mi = 0; mi < MI; ++mi) af[mi] = *(const bf16x8*)(bufA + offA[mi]);
    bf16x8 b0 = *(const bf16x8*)(bufB + offB[0]);
    bf16x8 b1 = *(const bf16x8*)(bufB + offB[1]);
    if (t + 2 < KT) stageA(t + 2, stg);
    __builtin_amdgcn_s_setprio(1);
    #pragma unroll
    for (int mi = 0; mi < MI; ++mi) {
      acc[mi][0] = __builtin_amdgcn_mfma_f32_16x16x32_bf16(af[mi], b0, acc[mi][0], 0, 0, 0);
      acc[mi][1] = __builtin_amdgcn_mfma_f32_16x16x32_bf16(af[mi], b1, acc[mi][1], 0, 0, 0);
    }
    __builtin_amdgcn_s_setprio(0);
    __builtin_amdgcn_s_barrier();               // phase lock

    // ---- phase 1: B frags {2,3}; stage B(t+2); MFMA half 2
    bf16x8 b2 = *(const bf16x8*)(bufB + offB[2]);
    bf16x8 b3 = *(const bf16x8*)(bufB + offB[3]);
    if (t + 2 < KT) stageB(t + 2, stg);
    __builtin_amdgcn_s_setprio(1);
    #pragma unroll
    for (int mi = 0; mi < MI; ++mi) {
      acc[mi][2] = __builtin_amdgcn_mfma_f32_16x16x32_bf16(af[mi], b2, acc[mi][2], 0, 0, 0);
      acc[mi][3] = __builtin_amdgcn_mfma_f32_16x16x32_bf16(af[mi], b3, acc[mi][3], 0, 0, 0);
    }
    __builtin_amdgcn_s_setprio(0);

    // tile boundary: leave only t+2's stages in flight (counted, not 0)
    if (t + 2 < KT) { if constexpr (S == 4) VMCNT(4); else VMCNT(3); }
    else            { VMCNT(0); }
    __builtin_amdgcn_s_barrier();
    __builtin_amdgcn_sched_barrier(0);
    cur = (cur == 2) ? 0 : cur + 1;
  }

  // Epilogue: bias (+relu/cast)
  #pragma unroll
  for (int ni = 0; ni < 4; ++ni) {
    int col = ncol0 + wc * 64 + ni * 16 + fl;
    float bv = bias[col];
    #pragma unroll
    for (int mi = 0; mi < MI; ++mi) {
      #pragma unroll
      for (int r = 0; r < 4; ++r) {
        long row = mrow0 + wr * (BM / 2) + mi * 16 + fh * 4 + r;
        float v = acc[mi][ni][r] + bv;
        if constexpr (RELU_OUT) {
          v = fmaxf(v, 0.0f);
          ((__bf16*)Cv)[row * NDIM + col] = (__bf16)v;
        } else {
          ((float*)Cv)[row * NDIM + col] = v;
        }
      }
    }
  }
}

// ---------------------------------------------------------------------------
// Fallback 128x128 GEMM (fp32 reg-staged A) -- used only if ws too small
// ---------------------------------------------------------------------------
template <int KD, int NB, bool AF32, bool RELU_OUT>
__global__ __launch_bounds__(256)
void gemm_mfma(const void* __restrict__ A0v, const void* __restrict__ A1v,
               const __bf16* __restrict__ Bt, const float* __restrict__ bias,
               void* __restrict__ Cv) {
  __shared__ __bf16 lA[128 * 32];
  __shared__ __bf16 lB[128 * 32];

  const int total_wg = (M1 / 128) * NB;
  int bid = blockIdx.x;
  const int q = total_wg >> 3;
  int swzb = (bid & 7) * q + (bid >> 3);
  const int mb = swzb / NB, nb = swzb % NB;
  const int mrow0 = mb * 128, ncol0 = nb * 128;
  const int NDIM = NB * 128;

  const int tid = threadIdx.x;
  const int wid = tid >> 6, lane = tid & 63;
  const int wr = wid >> 1, wc = wid & 1;
  const int fl = lane & 15, fh = lane >> 4;

  const float*  Af = nullptr;
  const __bf16* Ab = nullptr;
  if constexpr (AF32) {
    const float* A0 = (const float*)A0v;
    const float* A1 = (const float*)A1v;
    Af = (mrow0 < BATCH) ? (A0 + (size_t)mrow0 * KD)
                         : (A1 + (size_t)(mrow0 - BATCH) * KD);
  } else {
    Ab = (const __bf16*)A0v + (size_t)mrow0 * KD;
  }

  f32x4 acc[4][4] = {};
  const int a_row  = wid * 32 + (lane >> 2);
  const int a_slot = lane & 3;

  const int KT = KD / 32;
  for (int kt = 0; kt < KT; ++kt) {
    f32x4 av[2][2];
    if constexpr (AF32) {
      const float* ap = Af + (size_t)a_row * KD + kt * 32 + a_slot * 8;
      av[0][0] = *(const f32x4*)(ap);
      av[0][1] = *(const f32x4*)(ap + 4);
      av[1][0] = *(const f32x4*)(ap + (size_t)16 * KD);
      av[1][1] = *(const f32x4*)(ap + (size_t)16 * KD + 4);
    }
    __syncthreads();
    {
      int chunk = wid * 2;
      for (int c = 0; c < 2; ++c, ++chunk) {
        int row = chunk * 16 + (lane >> 2);
        int sslot = (lane & 3) ^ swz(row);
        const __bf16* srcp = Bt + (size_t)(ncol0 + row) * KD + kt * 32 + sslot * 8;
        gload_lds16(srcp, (void*)(lB + chunk * 512));
      }
    }
    if constexpr (AF32) {
      for (int r = 0; r < 2; ++r) {
        int row = a_row + r * 16;
        int sslot = a_slot ^ swz(row);
        bf16x8 w;
        for (int j = 0; j < 4; ++j) {
          w[j]     = (__bf16)av[r][0][j];
          w[4 + j] = (__bf16)av[r][1][j];
        }
        *(bf16x8*)(lA + row * 32 + sslot * 8) = w;
      }
    } else {
      int chunk = wid * 2;
      for (int c = 0; c < 2; ++c, ++chunk) {
        int row = chunk * 16 + (lane >> 2);
        int sslot = (lane & 3) ^ swz(row);
        const __bf16* srcp = Ab + (size_t)row * KD + kt * 32 + sslot * 8;
        gload_lds16(srcp, (void*)(lA + chunk * 512));
      }
    }
    __syncthreads();

    bf16x8 afr[4], bfr[4];
    for (int mi = 0; mi < 4; ++mi) {
      int row = wr * 64 + mi * 16 + fl;
      afr[mi] = *(const bf16x8*)(lA + row * 32 + (fh ^ swz(row)) * 8);
    }
    for (int ni = 0; ni < 4; ++ni) {
      int row = wc * 64 + ni * 16 + fl;
      bfr[ni] = *(const bf16x8*)(lB + row * 32 + (fh ^ swz(row)) * 8);
    }
    for (int mi = 0; mi < 4; ++mi)
      for (int ni = 0; ni < 4; ++ni)
        acc[mi][ni] = __builtin_amdgcn_mfma_f32_16x16x32_bf16(
            afr[mi], bfr[ni], acc[mi][ni], 0, 0, 0);
  }

  for (int ni = 0; ni < 4; ++ni) {
    int col = ncol0 + wc * 64 + ni * 16 + fl;
    float bv = bias[col];
    for (int mi = 0; mi < 4; ++mi) {
      for (int r = 0; r < 4; ++r) {
        size_t row = (size_t)mrow0 + wr * 64 + mi * 16 + fh * 4 + r;
        float v = acc[mi][ni][r] + bv;
        if constexpr (RELU_OUT) {
          v = fmaxf(v, 0.0f);
          ((__bf16*)Cv)[row * NDIM + col] = (__bf16)v;
        } else {
          ((float*)Cv)[row * NDIM + col] = v;
        }
      }
    }
  }
}

// ---------------------------------------------------------------------------
// LayerNorm + L2 normalize, in place on X [M1][256] f32. One wave per row.
// ---------------------------------------------------------------------------
__global__ __launch_bounds__(256)
void ln_l2_kernel(float* __restrict__ X, const float* __restrict__ g,
                  const float* __restrict__ be) {
  int row  = blockIdx.x * 4 + (threadIdx.x >> 6);
  int lane = threadIdx.x & 63;
  float* xp = X + (size_t)row * PDIM + lane * 4;
  f32x4 v = *(const f32x4*)xp;

  float s = v[0] + v[1] + v[2] + v[3];
  for (int m = 1; m < 64; m <<= 1) s += __shfl_xor(s, m, 64);
  float mu = s * (1.0f / PDIM);

  f32x4 d;
  for (int j = 0; j < 4; ++j) d[j] = v[j] - mu;
  float qv = dot4(d, d);
  for (int m = 1; m < 64; m <<= 1) qv += __shfl_xor(qv, m, 64);
  float rs = rsqrtf(qv * (1.0f / PDIM) + 1e-5f);

  f32x4 g4 = *(const f32x4*)(g + lane * 4);
  f32x4 b4 = *(const f32x4*)(be + lane * 4);
  f32x4 y;
  for (int j = 0; j < 4; ++j) y[j] = d[j] * rs * g4[j] + b4[j];

  float n2 = dot4(y, y);
  for (int m = 1; m < 64; m <<= 1) n2 += __shfl_xor(n2, m, 64);
  float sc = 1.0f / fmaxf(sqrtf(n2), 1e-12f);
  for (int j = 0; j < 4; ++j) y[j] *= sc;
  *(f32x4*)xp = y;
}

// ---------------------------------------------------------------------------
// Per-row contrastive loss.
// ---------------------------------------------------------------------------
__global__ __launch_bounds__(256)
void loss_kernel(const float* __restrict__ X, const float* __restrict__ negbuf,
                 const int* __restrict__ nidx, float* __restrict__ partials) {
  __shared__ float lsum[4];
  int b    = blockIdx.x * 4 + (threadIdx.x >> 6);
  int lane = threadIdx.x & 63;
  int g = lane >> 4, lg = lane & 15;

  const float* arow = X + (size_t)b * PDIM;
  const float* prow = X + (size_t)(BATCH + b) * PDIM;

  f32x4 a4[4];
  for (int j = 0; j < 4; ++j) a4[j] = *(const f32x4*)(arow + lg * 16 + j * 4);

  float ps = 0.0f;
  for (int j = 0; j < 4; ++j) {
    f32x4 p = *(const f32x4*)(prow + lg * 16 + j * 4);
    ps += dot4(a4[j], p);
  }
  for (int m = 1; m < 16; m <<= 1) ps += __shfl_xor(ps, m, 64);
  float pos = ps * 2.0f;  // /TEMPERATURE

  float myneg = -3.0e38f;
  for (int k4 = 0; k4 < 16; ++k4) {
    int k = k4 * 4 + g;
    int idx = nidx[(size_t)b * KNEG + k];
    const float* nrow = negbuf + (size_t)idx * PDIM;
    float sv = 0.0f;
    for (int j = 0; j < 4; ++j) {
      f32x4 nv = *(const f32x4*)(nrow + lg * 16 + j * 4);
      sv += dot4(a4[j], nv);
    }
    for (int m = 1; m < 16; m <<= 1) sv += __shfl_xor(sv, m, 64);
    if (lg == k4) myneg = sv * 2.0f;
  }

  float mx = myneg;
  for (int m = 1; m < 64; m <<= 1) mx = fmaxf(mx, __shfl_xor(mx, m, 64));
  mx = fmaxf(mx, pos);
  float e = expf(myneg - mx);
  for (int m = 1; m < 64; m <<= 1) e += __shfl_xor(e, m, 64);
  float tot = e + expf(pos - mx);
  float lb = -(pos - mx - logf(tot));

  if (lane == 0) lsum[threadIdx.x >> 6] = lb;
  __syncthreads();
  if (threadIdx.x == 0)
    partials[blockIdx.x] = lsum[0] + lsum[1] + lsum[2] + lsum[3];
}

__global__ void finalize_kernel(const float* __restrict__ partials,
                                float* __restrict__ out) {
  __shared__ float ls[4];
  int tid = threadIdx.x;
  float s = 0.0f;
  for (int i = tid; i < 4096; i += 256) s += partials[i];
  for (int m = 1; m < 64; m <<= 1) s += __shfl_xor(s, m, 64);
  if ((tid & 63) == 0) ls[tid >> 6] = s;
  __syncthreads();
  if (tid == 0) out[0] = (ls[0] + ls[1] + ls[2] + ls[3]) * (1.0f / BATCH);
}

// ---------------------------------------------------------------------------
extern "C" void kernel_launch(void* const* d_in, const int* in_sizes, int n_in,
                              void* d_out, int out_size, void* d_ws, size_t ws_size,
                              hipStream_t stream) {
  const float* hidden   = (const float*)d_in[0];
  const float* positive = (const float*)d_in[1];
  const float* negbuf   = (const float*)d_in[2];
  const float* W1       = (const float*)d_in[3];
  const float* b1       = (const float*)d_in[4];
  const float* W2       = (const float*)d_in[5];
  const float* b2       = (const float*)d_in[6];
  const float* gamma    = (const float*)d_in[7];
  const float* beta     = (const float*)d_in[8];
  const int*   nidx     = (const int*)d_in[9];
  float* out = (float*)d_out;

  char* ws = (char*)d_ws;

  const size_t OFF_Y1   = 134217728;
  const size_t OFF_W1T  = OFF_Y1 + 67108864;
  const size_t OFF_W2T  = OFF_W1T + 4194304;
  const size_t OFF_PART = OFF_W2T + 524288;
  const size_t NEED_BIG = OFF_PART + 16384;

  const bool big = (ws_size >= NEED_BIG);

  __bf16* W1T; __bf16* W2T; __bf16* Y1; float* X; float* partials;
  __bf16* Abf = nullptr;
  if (big) {
    Abf      = (__bf16*)(ws);
    Y1       = (__bf16*)(ws + OFF_Y1);
    W1T      = (__bf16*)(ws + OFF_W1T);
    W2T      = (__bf16*)(ws + OFF_W2T);
    partials = (float*) (ws + OFF_PART);
    X        = (float*) (ws);  // overlaps dead Abf
  } else {
    W1T      = (__bf16*)(ws);
    W2T      = (__bf16*)(ws + 4194304);
    Y1       = (__bf16*)(ws + 4718592);
    X        = (float*) (ws + 71827456);
    partials = (float*) (ws + 105381888);
  }

  transpose_cast_kernel<<<dim3(HHDIM / 32, HDIM / 32), dim3(32, 8), 0, stream>>>(
      W1, W1T, HDIM, HHDIM);
  transpose_cast_kernel<<<dim3(PDIM / 32, HHDIM / 32), dim3(32, 8), 0, stream>>>(
      W2, W2T, HHDIM, PDIM);

  if (big) {
    const long n8 = (long)BATCH * HDIM / 8;
    cast_bf16_kernel<<<2048, 256, 0, stream>>>(hidden, Abf, n8);
    cast_bf16_kernel<<<2048, 256, 0, stream>>>(positive, Abf + (size_t)BATCH * HDIM, n8);

    // GEMM1: [32768,2048] @ [2048,1024]^T + b1, relu -> Y1 (bf16)
    gemm_pipe<HDIM, 256, HHDIM / 256, true, (M1 / 256) * (HHDIM / 256)>
        <<<(M1 / 256) * (HHDIM / 256), 512, 0, stream>>>(Abf, W1T, b1, Y1);

    // GEMM2: [32768,1024] @ [1024,256]^T + b2 -> X (f32)
    gemm_pipe<HHDIM, 128, PDIM / 256, false, (M1 / 128) * (PDIM / 256)>
        <<<(M1 / 128) * (PDIM / 256), 512, 0, stream>>>(Y1, W2T, b2, X);
  } else {
    gemm_mfma<HDIM, HHDIM / 128, true, true>
        <<<(M1 / 128) * (HHDIM / 128), 256, 0, stream>>>(
            hidden, positive, W1T, b1, Y1);
    gemm_mfma<HHDIM, PDIM / 128, false, false>
        <<<(M1 / 128) * (PDIM / 128), 256, 0, stream>>>(
            Y1, nullptr, W2T, b2, X);
  }

  ln_l2_kernel<<<M1 / 4, 256, 0, stream>>>(X, gamma, beta);
  loss_kernel<<<BATCH / 4, 256, 0, stream>>>(X, negbuf, nidx, partials);
  finalize_kernel<<<1, 256, 0, stream>>>(partials, out);
}

// Round 5
// 348.859 us; speedup vs baseline: 1.1236x; 1.0261x over previous
//
#include <hip/hip_runtime.h>
#include <hip/hip_bf16.h>
#include <cstdint>

// Problem constants
#define BATCH   16384
#define HDIM    2048
#define HHDIM   1024
#define PDIM    256
#define KNEG    64
#define NBUF    2000
#define M1      (2 * BATCH)          // 32768 rows through the projection head

typedef float  f32x4  __attribute__((ext_vector_type(4)));
typedef __bf16 bf16x8 __attribute__((ext_vector_type(8)));

typedef __attribute__((address_space(3))) unsigned int       lds_u32;
typedef __attribute__((address_space(1))) const unsigned int glb_u32;

__device__ __forceinline__ void gload_lds16(const void* g, void* l) {
  __builtin_amdgcn_global_load_lds((glb_u32*)g, (lds_u32*)l, 16, 0, 0);
}

__device__ __forceinline__ float dot4(f32x4 a, f32x4 b) {
  return a[0]*b[0] + a[1]*b[1] + a[2]*b[2] + a[3]*b[3];
}

#define VMCNT(n) asm volatile("s_waitcnt vmcnt(" #n ")" ::: "memory")

// ---------------------------------------------------------------------------
// f32 -> bf16 cast, 8 elems/thread, grid-stride
// ---------------------------------------------------------------------------
__global__ __launch_bounds__(256)
void cast_bf16_kernel(const float* __restrict__ src, __bf16* __restrict__ dst,
                      long n8) {
  long i = (long)blockIdx.x * blockDim.x + threadIdx.x;
  long stride = (long)gridDim.x * blockDim.x;
  for (; i < n8; i += stride) {
    f32x4 a = ((const f32x4*)src)[2 * i];
    f32x4 b = ((const f32x4*)src)[2 * i + 1];
    bf16x8 w;
    for (int j = 0; j < 4; ++j) { w[j] = (__bf16)a[j]; w[4 + j] = (__bf16)b[j]; }
    ((bf16x8*)dst)[i] = w;
  }
}

// ---------------------------------------------------------------------------
// Transpose + cast: src [K][N] f32 row-major  ->  dst [N][K] bf16 row-major
// ---------------------------------------------------------------------------
__global__ void transpose_cast_kernel(const float* __restrict__ src,
                                      __bf16* __restrict__ dst, int K, int N) {
  __shared__ float tile[32][33];
  int bn = blockIdx.x * 32, bk = blockIdx.y * 32;
  int tx = threadIdx.x, ty = threadIdx.y;  // 32 x 8
  for (int j = 0; j < 32; j += 8)
    tile[ty + j][tx] = src[(size_t)(bk + ty + j) * N + bn + tx];
  __syncthreads();
  for (int j = 0; j < 32; j += 8)
    dst[(size_t)(bn + ty + j) * K + bk + tx] = (__bf16)tile[tx][ty + j];
}

// ---------------------------------------------------------------------------
// 8-phase 256x256 MFMA GEMM (T2+T3+T4+T5).
//   C[M][NBt*256] = A[M][KD] @ Bt[NBt*256][KD]^T + bias
//   512 threads = 8 waves (2M x 4N). BK = 64. LDS: 2 bufs x (A 256x64 + B 256x64).
//   Each phase = one global 128x128 C-quadrant x K=64 (16 MFMA/wave):
//     p1 Q(0,0): read A-half0 (8 b128) + B-half0 (4); stage B0(s+1)
//     p2 Q(0,1): read B-half1 (4);                    stage A1(s+1)
//     p3 Q(1,1): read A-half1 (8);                    stage A0(s+2)
//     p4 Q(1,0): read B-half0 (4, re-read);           stage B1(s+2)
//   Write-safety: each stage target's last reader finished >=1 barrier before
//   the stage issue (A0(s) free after p2(s); B1(s) after p3(s); A1/B0 of the
//   other buffer free after p4(s-1)).
//   Landing: boundary VMCNT(4) leaves exactly {A0(s+2), B1(s+2)} (newest 4
//   loads) in flight => B0(s+1), A1(s+1) and older have landed.
//   LDS swizzle: row stride 128B; slot' = slot ^ (row&7) -> <=2 lanes/bank.
// ---------------------------------------------------------------------------
template <int KD, int NBt, bool RELU_OUT, int GRID>
__global__ __launch_bounds__(512)
void gemm_8ph(const __bf16* __restrict__ A, const __bf16* __restrict__ Bt,
              const float* __restrict__ bias, void* __restrict__ Cv) {
  constexpr int KT   = KD / 64;       // K-steps
  constexpr int HALF = 128 * 64;      // elems per half-tile
  constexpr int STEP = 2 * HALF;      // elems per buf (one K-step, 2 halves)
  constexpr int NDIM = NBt * 256;

  __shared__ __bf16 lA[2 * STEP];     // 64 KB
  __shared__ __bf16 lB[2 * STEP];     // 64 KB

  constexpr int Q = GRID / 8;         // XCD-bijective swizzle (GRID % 8 == 0)
  int bid = blockIdx.x;
  int swb = (bid & 7) * Q + (bid >> 3);
  const int mb = swb / NBt, nb = swb % NBt;
  const long mrow0 = (long)mb * 256;
  const int  ncol0 = nb * 256;

  const int tid = threadIdx.x;
  const int wid = tid >> 6, lane = tid & 63;
  const int wr = wid >> 2, wc = wid & 3;     // 2 x 4 wave grid
  const int fl = lane & 15, fh = lane >> 4;

  // ds-read element offsets within a half-tile
  int aoff[4][2], boff[2][2];
  #pragma unroll
  for (int mi = 0; mi < 4; ++mi)
    #pragma unroll
    for (int ks = 0; ks < 2; ++ks) {
      int row = wr * 64 + mi * 16 + fl;
      aoff[mi][ks] = row * 64 + (((ks * 4 + fh) ^ (row & 7)) * 8);
    }
  #pragma unroll
  for (int ni = 0; ni < 2; ++ni)
    #pragma unroll
    for (int ks = 0; ks < 2; ++ks) {
      int row = wc * 32 + ni * 16 + fl;
      boff[ni][ks] = row * 64 + (((ks * 4 + fh) ^ (row & 7)) * 8);
    }

  // Staging: half-tile = 128 rows x 64 K; thread covers dest bytes
  // tid*16 + i*8192 -> row = (tid>>3)+i*64, slot = tid&7 (pre-swizzled source).
  const int r0 = tid >> 3, sl = tid & 7;
  long aS[2][2], bS[2][2];                   // [half][i] element offsets
  #pragma unroll
  for (int h = 0; h < 2; ++h)
    #pragma unroll
    for (int i = 0; i < 2; ++i) {
      int rr = r0 + i * 64;
      int ss = sl ^ (rr & 7);
      aS[h][i] = (mrow0 + h * 128 + rr) * (long)KD + ss * 8;
      bS[h][i] = ((long)(ncol0 + h * 128 + rr)) * KD + ss * 8;
    }
  const int dstw = wid * 512;                // wave-uniform dest chunk (elems)

  auto stA = [&](int h, int t) {
    __bf16* base = lA + (t & 1) * STEP + h * HALF + dstw;
    gload_lds16(A + aS[h][0] + (long)t * 64, (void*)(base));
    gload_lds16(A + aS[h][1] + (long)t * 64, (void*)(base + 4096));
  };
  auto stB = [&](int h, int t) {
    __bf16* base = lB + (t & 1) * STEP + h * HALF + dstw;
    gload_lds16(Bt + bS[h][0] + (long)t * 64, (void*)(base));
    gload_lds16(Bt + bS[h][1] + (long)t * 64, (void*)(base + 4096));
  };

  bf16x8 areg[4][2], breg[2][2];
  auto loadA = [&](int mh, int s) {
    const __bf16* base = lA + (s & 1) * STEP + mh * HALF;
    #pragma unroll
    for (int mi = 0; mi < 4; ++mi)
      #pragma unroll
      for (int ks = 0; ks < 2; ++ks)
        areg[mi][ks] = *(const bf16x8*)(base + aoff[mi][ks]);
  };
  auto loadB = [&](int nh, int s) {
    const __bf16* base = lB + (s & 1) * STEP + nh * HALF;
    #pragma unroll
    for (int ni = 0; ni < 2; ++ni)
      #pragma unroll
      for (int ks = 0; ks < 2; ++ks)
        breg[ni][ks] = *(const bf16x8*)(base + boff[ni][ks]);
  };

  f32x4 acc[2][2][4][2] = {};

#define MFMA2(mh, nh, mi, ni)                                                 \
  acc[mh][nh][mi][ni] = __builtin_amdgcn_mfma_f32_16x16x32_bf16(              \
      areg[mi][0], breg[ni][0], acc[mh][nh][mi][ni], 0, 0, 0);                \
  acc[mh][nh][mi][ni] = __builtin_amdgcn_mfma_f32_16x16x32_bf16(              \
      areg[mi][1], breg[ni][1], acc[mh][nh][mi][ni], 0, 0, 0);

#define PHASE_MFMA(mh, nh)                                                    \
  __builtin_amdgcn_s_setprio(1);                                              \
  MFMA2(mh, nh, 0, 0) MFMA2(mh, nh, 0, 1)                                     \
  MFMA2(mh, nh, 1, 0) MFMA2(mh, nh, 1, 1)                                     \
  MFMA2(mh, nh, 2, 0) MFMA2(mh, nh, 2, 1)                                     \
  MFMA2(mh, nh, 3, 0) MFMA2(mh, nh, 3, 1)                                     \
  __builtin_amdgcn_s_setprio(0);

  // Prologue: stage steps 0 and 1 fully; wait step 0 (leave step 1 in flight)
  stA(0, 0); stB(0, 0); stA(1, 0); stB(1, 0);
  stA(0, 1); stB(1, 1); stB(0, 1); stA(1, 1);
  VMCNT(8);
  __builtin_amdgcn_s_barrier();
  __builtin_amdgcn_sched_barrier(0);

  for (int s = 0; s < KT; ++s) {
    // ---- phase 1: Q(0,0)
    loadA(0, s); loadB(0, s);
    if (s >= 1 && s + 1 < KT) stB(0, s + 1);
    __builtin_amdgcn_s_barrier();
    PHASE_MFMA(0, 0);
    __builtin_amdgcn_s_barrier();

    // ---- phase 2: Q(0,1)
    loadB(1, s);
    if (s >= 1 && s + 1 < KT) stA(1, s + 1);
    __builtin_amdgcn_s_barrier();
    PHASE_MFMA(0, 1);
    __builtin_amdgcn_s_barrier();

    // ---- phase 3: Q(1,1)
    loadA(1, s);
    if (s + 2 < KT) stA(0, s + 2);
    __builtin_amdgcn_s_barrier();
    PHASE_MFMA(1, 1);
    __builtin_amdgcn_s_barrier();

    // ---- phase 4: Q(1,0)
    loadB(0, s);
    if (s + 2 < KT) stB(1, s + 2);
    __builtin_amdgcn_s_barrier();
    PHASE_MFMA(1, 0);
    if (s + 2 < KT) { VMCNT(4); } else { VMCNT(0); }
    __builtin_amdgcn_s_barrier();
    __builtin_amdgcn_sched_barrier(0);
  }

#undef PHASE_MFMA
#undef MFMA2

  // Epilogue: bias (+relu/cast)
  #pragma unroll
  for (int mh = 0; mh < 2; ++mh)
    #pragma unroll
    for (int nh = 0; nh < 2; ++nh)
      #pragma unroll
      for (int ni = 0; ni < 2; ++ni) {
        int col = ncol0 + nh * 128 + wc * 32 + ni * 16 + fl;
        float bv = bias[col];
        #pragma unroll
        for (int mi = 0; mi < 4; ++mi)
          #pragma unroll
          for (int r = 0; r < 4; ++r) {
            long row = mrow0 + mh * 128 + wr * 64 + mi * 16 + fh * 4 + r;
            float v = acc[mh][nh][mi][ni][r] + bv;
            if constexpr (RELU_OUT) {
              v = fmaxf(v, 0.0f);
              ((__bf16*)Cv)[row * NDIM + col] = (__bf16)v;
            } else {
              ((float*)Cv)[row * NDIM + col] = v;
            }
          }
      }
}

// ---------------------------------------------------------------------------
// Fallback 128x128 GEMM (fp32 reg-staged A) -- used only if ws too small
// ---------------------------------------------------------------------------
__device__ __forceinline__ int swz(int row) { return (row >> 1) & 3; }

template <int KD, int NB, bool AF32, bool RELU_OUT>
__global__ __launch_bounds__(256)
void gemm_mfma(const void* __restrict__ A0v, const void* __restrict__ A1v,
               const __bf16* __restrict__ Bt, const float* __restrict__ bias,
               void* __restrict__ Cv) {
  __shared__ __bf16 lA[128 * 32];
  __shared__ __bf16 lB[128 * 32];

  const int total_wg = (M1 / 128) * NB;
  int bid = blockIdx.x;
  const int q = total_wg >> 3;
  int swzb = (bid & 7) * q + (bid >> 3);
  const int mb = swzb / NB, nb = swzb % NB;
  const int mrow0 = mb * 128, ncol0 = nb * 128;
  const int NDIM = NB * 128;

  const int tid = threadIdx.x;
  const int wid = tid >> 6, lane = tid & 63;
  const int wr = wid >> 1, wc = wid & 1;
  const int fl = lane & 15, fh = lane >> 4;

  const float*  Af = nullptr;
  const __bf16* Ab = nullptr;
  if constexpr (AF32) {
    const float* A0 = (const float*)A0v;
    const float* A1 = (const float*)A1v;
    Af = (mrow0 < BATCH) ? (A0 + (size_t)mrow0 * KD)
                         : (A1 + (size_t)(mrow0 - BATCH) * KD);
  } else {
    Ab = (const __bf16*)A0v + (size_t)mrow0 * KD;
  }

  f32x4 acc[4][4] = {};
  const int a_row  = wid * 32 + (lane >> 2);
  const int a_slot = lane & 3;

  const int KT = KD / 32;
  for (int kt = 0; kt < KT; ++kt) {
    f32x4 av[2][2];
    if constexpr (AF32) {
      const float* ap = Af + (size_t)a_row * KD + kt * 32 + a_slot * 8;
      av[0][0] = *(const f32x4*)(ap);
      av[0][1] = *(const f32x4*)(ap + 4);
      av[1][0] = *(const f32x4*)(ap + (size_t)16 * KD);
      av[1][1] = *(const f32x4*)(ap + (size_t)16 * KD + 4);
    }
    __syncthreads();
    {
      int chunk = wid * 2;
      for (int c = 0; c < 2; ++c, ++chunk) {
        int row = chunk * 16 + (lane >> 2);
        int sslot = (lane & 3) ^ swz(row);
        const __bf16* srcp = Bt + (size_t)(ncol0 + row) * KD + kt * 32 + sslot * 8;
        gload_lds16(srcp, (void*)(lB + chunk * 512));
      }
    }
    if constexpr (AF32) {
      for (int r = 0; r < 2; ++r) {
        int row = a_row + r * 16;
        int sslot = a_slot ^ swz(row);
        bf16x8 w;
        for (int j = 0; j < 4; ++j) {
          w[j]     = (__bf16)av[r][0][j];
          w[4 + j] = (__bf16)av[r][1][j];
        }
        *(bf16x8*)(lA + row * 32 + sslot * 8) = w;
      }
    } else {
      int chunk = wid * 2;
      for (int c = 0; c < 2; ++c, ++chunk) {
        int row = chunk * 16 + (lane >> 2);
        int sslot = (lane & 3) ^ swz(row);
        const __bf16* srcp = Ab + (size_t)row * KD + kt * 32 + sslot * 8;
        gload_lds16(srcp, (void*)(lA + chunk * 512));
      }
    }
    __syncthreads();

    bf16x8 afr[4], bfr[4];
    for (int mi = 0; mi < 4; ++mi) {
      int row = wr * 64 + mi * 16 + fl;
      afr[mi] = *(const bf16x8*)(lA + row * 32 + (fh ^ swz(row)) * 8);
    }
    for (int ni = 0; ni < 4; ++ni) {
      int row = wc * 64 + ni * 16 + fl;
      bfr[ni] = *(const bf16x8*)(lB + row * 32 + (fh ^ swz(row)) * 8);
    }
    for (int mi = 0; mi < 4; ++mi)
      for (int ni = 0; ni < 4; ++ni)
        acc[mi][ni] = __builtin_amdgcn_mfma_f32_16x16x32_bf16(
            afr[mi], bfr[ni], acc[mi][ni], 0, 0, 0);
  }

  for (int ni = 0; ni < 4; ++ni) {
    int col = ncol0 + wc * 64 + ni * 16 + fl;
    float bv = bias[col];
    for (int mi = 0; mi < 4; ++mi) {
      for (int r = 0; r < 4; ++r) {
        size_t row = (size_t)mrow0 + wr * 64 + mi * 16 + fh * 4 + r;
        float v = acc[mi][ni][r] + bv;
        if constexpr (RELU_OUT) {
          v = fmaxf(v, 0.0f);
          ((__bf16*)Cv)[row * NDIM + col] = (__bf16)v;
        } else {
          ((float*)Cv)[row * NDIM + col] = v;
        }
      }
    }
  }
}

// ---------------------------------------------------------------------------
// LayerNorm + L2 normalize, in place on X [M1][256] f32. One wave per row.
// ---------------------------------------------------------------------------
__global__ __launch_bounds__(256)
void ln_l2_kernel(float* __restrict__ X, const float* __restrict__ g,
                  const float* __restrict__ be) {
  int row  = blockIdx.x * 4 + (threadIdx.x >> 6);
  int lane = threadIdx.x & 63;
  float* xp = X + (size_t)row * PDIM + lane * 4;
  f32x4 v = *(const f32x4*)xp;

  float s = v[0] + v[1] + v[2] + v[3];
  for (int m = 1; m < 64; m <<= 1) s += __shfl_xor(s, m, 64);
  float mu = s * (1.0f / PDIM);

  f32x4 d;
  for (int j = 0; j < 4; ++j) d[j] = v[j] - mu;
  float qv = dot4(d, d);
  for (int m = 1; m < 64; m <<= 1) qv += __shfl_xor(qv, m, 64);
  float rs = rsqrtf(qv * (1.0f / PDIM) + 1e-5f);

  f32x4 g4 = *(const f32x4*)(g + lane * 4);
  f32x4 b4 = *(const f32x4*)(be + lane * 4);
  f32x4 y;
  for (int j = 0; j < 4; ++j) y[j] = d[j] * rs * g4[j] + b4[j];

  float n2 = dot4(y, y);
  for (int m = 1; m < 64; m <<= 1) n2 += __shfl_xor(n2, m, 64);
  float sc = 1.0f / fmaxf(sqrtf(n2), 1e-12f);
  for (int j = 0; j < 4; ++j) y[j] *= sc;
  *(f32x4*)xp = y;
}

// ---------------------------------------------------------------------------
// Per-row contrastive loss.
// ---------------------------------------------------------------------------
__global__ __launch_bounds__(256)
void loss_kernel(const float* __restrict__ X, const float* __restrict__ negbuf,
                 const int* __restrict__ nidx, float* __restrict__ partials) {
  __shared__ float lsum[4];
  int b    = blockIdx.x * 4 + (threadIdx.x >> 6);
  int lane = threadIdx.x & 63;
  int g = lane >> 4, lg = lane & 15;

  const float* arow = X + (size_t)b * PDIM;
  const float* prow = X + (size_t)(BATCH + b) * PDIM;

  f32x4 a4[4];
  for (int j = 0; j < 4; ++j) a4[j] = *(const f32x4*)(arow + lg * 16 + j * 4);

  float ps = 0.0f;
  for (int j = 0; j < 4; ++j) {
    f32x4 p = *(const f32x4*)(prow + lg * 16 + j * 4);
    ps += dot4(a4[j], p);
  }
  for (int m = 1; m < 16; m <<= 1) ps += __shfl_xor(ps, m, 64);
  float pos = ps * 2.0f;  // /TEMPERATURE

  float myneg = -3.0e38f;
  for (int k4 = 0; k4 < 16; ++k4) {
    int k = k4 * 4 + g;
    int idx = nidx[(size_t)b * KNEG + k];
    const float* nrow = negbuf + (size_t)idx * PDIM;
    float sv = 0.0f;
    for (int j = 0; j < 4; ++j) {
      f32x4 nv = *(const f32x4*)(nrow + lg * 16 + j * 4);
      sv += dot4(a4[j], nv);
    }
    for (int m = 1; m < 16; m <<= 1) sv += __shfl_xor(sv, m, 64);
    if (lg == k4) myneg = sv * 2.0f;
  }

  float mx = myneg;
  for (int m = 1; m < 64; m <<= 1) mx = fmaxf(mx, __shfl_xor(mx, m, 64));
  mx = fmaxf(mx, pos);
  float e = expf(myneg - mx);
  for (int m = 1; m < 64; m <<= 1) e += __shfl_xor(e, m, 64);
  float tot = e + expf(pos - mx);
  float lb = -(pos - mx - logf(tot));

  if (lane == 0) lsum[threadIdx.x >> 6] = lb;
  __syncthreads();
  if (threadIdx.x == 0)
    partials[blockIdx.x] = lsum[0] + lsum[1] + lsum[2] + lsum[3];
}

__global__ void finalize_kernel(const float* __restrict__ partials,
                                float* __restrict__ out) {
  __shared__ float ls[4];
  int tid = threadIdx.x;
  float s = 0.0f;
  for (int i = tid; i < 4096; i += 256) s += partials[i];
  for (int m = 1; m < 64; m <<= 1) s += __shfl_xor(s, m, 64);
  if ((tid & 63) == 0) ls[tid >> 6] = s;
  __syncthreads();
  if (tid == 0) out[0] = (ls[0] + ls[1] + ls[2] + ls[3]) * (1.0f / BATCH);
}

// ---------------------------------------------------------------------------
extern "C" void kernel_launch(void* const* d_in, const int* in_sizes, int n_in,
                              void* d_out, int out_size, void* d_ws, size_t ws_size,
                              hipStream_t stream) {
  const float* hidden   = (const float*)d_in[0];
  const float* positive = (const float*)d_in[1];
  const float* negbuf   = (const float*)d_in[2];
  const float* W1       = (const float*)d_in[3];
  const float* b1       = (const float*)d_in[4];
  const float* W2       = (const float*)d_in[5];
  const float* b2       = (const float*)d_in[6];
  const float* gamma    = (const float*)d_in[7];
  const float* beta     = (const float*)d_in[8];
  const int*   nidx     = (const int*)d_in[9];
  float* out = (float*)d_out;

  char* ws = (char*)d_ws;

  const size_t OFF_Y1   = 134217728;
  const size_t OFF_W1T  = OFF_Y1 + 67108864;
  const size_t OFF_W2T  = OFF_W1T + 4194304;
  const size_t OFF_PART = OFF_W2T + 524288;
  const size_t NEED_BIG = OFF_PART + 16384;

  const bool big = (ws_size >= NEED_BIG);

  __bf16* W1T; __bf16* W2T; __bf16* Y1; float* X; float* partials;
  __bf16* Abf = nullptr;
  if (big) {
    Abf      = (__bf16*)(ws);
    Y1       = (__bf16*)(ws + OFF_Y1);
    W1T      = (__bf16*)(ws + OFF_W1T);
    W2T      = (__bf16*)(ws + OFF_W2T);
    partials = (float*) (ws + OFF_PART);
    X        = (float*) (ws);  // overlaps dead Abf
  } else {
    W1T      = (__bf16*)(ws);
    W2T      = (__bf16*)(ws + 4194304);
    Y1       = (__bf16*)(ws + 4718592);
    X        = (float*) (ws + 71827456);
    partials = (float*) (ws + 105381888);
  }

  transpose_cast_kernel<<<dim3(HHDIM / 32, HDIM / 32), dim3(32, 8), 0, stream>>>(
      W1, W1T, HDIM, HHDIM);
  transpose_cast_kernel<<<dim3(PDIM / 32, HHDIM / 32), dim3(32, 8), 0, stream>>>(
      W2, W2T, HHDIM, PDIM);

  if (big) {
    const long n8 = (long)BATCH * HDIM / 8;
    cast_bf16_kernel<<<2048, 256, 0, stream>>>(hidden, Abf, n8);
    cast_bf16_kernel<<<2048, 256, 0, stream>>>(positive, Abf + (size_t)BATCH * HDIM, n8);

    // GEMM1: [32768,2048] @ [2048,1024]^T + b1, relu -> Y1 (bf16)
    gemm_8ph<HDIM, HHDIM / 256, true, (M1 / 256) * (HHDIM / 256)>
        <<<(M1 / 256) * (HHDIM / 256), 512, 0, stream>>>(Abf, W1T, b1, Y1);

    // GEMM2: [32768,1024] @ [1024,256]^T + b2 -> X (f32)
    gemm_8ph<HHDIM, PDIM / 256, false, (M1 / 256) * (PDIM / 256)>
        <<<(M1 / 256) * (PDIM / 256), 512, 0, stream>>>(Y1, W2T, b2, X);
  } else {
    gemm_mfma<HDIM, HHDIM / 128, true, true>
        <<<(M1 / 128) * (HHDIM / 128), 256, 0, stream>>>(
            hidden, positive, W1T, b1, Y1);
    gemm_mfma<HHDIM, PDIM / 128, false, false>
        <<<(M1 / 128) * (PDIM / 128), 256, 0, stream>>>(
            Y1, nullptr, W2T, b2, X);
  }

  ln_l2_kernel<<<M1 / 4, 256, 0, stream>>>(X, gamma, beta);
  loss_kernel<<<BATCH / 4, 256, 0, stream>>>(X, negbuf, nidx, partials);
  finalize_kernel<<<1, 256, 0, stream>>>(partials, out);
}

// Round 6
// 339.363 us; speedup vs baseline: 1.1550x; 1.0280x over previous
//
#include <hip/hip_runtime.h>
#include <hip/hip_bf16.h>
#include <cstdint>

// Problem constants
#define BATCH   16384
#define HDIM    2048
#define HHDIM   1024
#define PDIM    256
#define KNEG    64
#define NBUF    2000
#define M1      (2 * BATCH)          // 32768 rows through the projection head

typedef float  f32x4  __attribute__((ext_vector_type(4)));
typedef __bf16 bf16x8 __attribute__((ext_vector_type(8)));

typedef __attribute__((address_space(3))) unsigned int       lds_u32;
typedef __attribute__((address_space(1))) const unsigned int glb_u32;

__device__ __forceinline__ void gload_lds16(const void* g, void* l) {
  __builtin_amdgcn_global_load_lds((glb_u32*)g, (lds_u32*)l, 16, 0, 0);
}

__device__ __forceinline__ float dot4(f32x4 a, f32x4 b) {
  return a[0]*b[0] + a[1]*b[1] + a[2]*b[2] + a[3]*b[3];
}

#define VMCNT(n) asm volatile("s_waitcnt vmcnt(" #n ")" ::: "memory")
#define LGKM(n)  asm volatile("s_waitcnt lgkmcnt(" #n ")" ::: "memory")

// ---------------------------------------------------------------------------
// f32 -> bf16 cast, 8 elems/thread, grid-stride
// ---------------------------------------------------------------------------
__global__ __launch_bounds__(256)
void cast_bf16_kernel(const float* __restrict__ src, __bf16* __restrict__ dst,
                      long n8) {
  long i = (long)blockIdx.x * blockDim.x + threadIdx.x;
  long stride = (long)gridDim.x * blockDim.x;
  for (; i < n8; i += stride) {
    f32x4 a = ((const f32x4*)src)[2 * i];
    f32x4 b = ((const f32x4*)src)[2 * i + 1];
    bf16x8 w;
    for (int j = 0; j < 4; ++j) { w[j] = (__bf16)a[j]; w[4 + j] = (__bf16)b[j]; }
    ((bf16x8*)dst)[i] = w;
  }
}

// ---------------------------------------------------------------------------
// Transpose + cast: src [K][N] f32 row-major  ->  dst [N][K] bf16 row-major
// ---------------------------------------------------------------------------
__global__ void transpose_cast_kernel(const float* __restrict__ src,
                                      __bf16* __restrict__ dst, int K, int N) {
  __shared__ float tile[32][33];
  int bn = blockIdx.x * 32, bk = blockIdx.y * 32;
  int tx = threadIdx.x, ty = threadIdx.y;  // 32 x 8
  for (int j = 0; j < 32; j += 8)
    tile[ty + j][tx] = src[(size_t)(bk + ty + j) * N + bn + tx];
  __syncthreads();
  for (int j = 0; j < 32; j += 8)
    dst[(size_t)(bn + ty + j) * K + bk + tx] = (__bf16)tile[tx][ty + j];
}

// ---------------------------------------------------------------------------
// 8-phase (2*BMH)x256 MFMA GEMM (T2+T3+T4+T5), ks-outer MFMA ordering.
//   C[M][NBt*256] = A[M][KD] @ Bt[NBt*256][KD]^T + bias
//   512 threads = 8 waves (2M x 4N). BK = 64.
//   LDS: 2 bufs x {A: 2 half x BMH x 64, B: 2 half x 128 x 64} bf16.
//   Quadrant phases per K-step s:
//     p1 Q(0,0): ds-read A0(2*MI)+B0(4) -> breg0; stage B0(s+1)
//     p2 Q(0,1): ds-read B1(4) -> breg1 (A0 held);  stage A1(s+1)
//     p3 Q(1,1): ds-read A1 (breg1 held);           stage A0(s+2)
//     p4 Q(1,0): no reads (areg1+breg0 held);       stage B1(s+2)
//   MFMA per phase: ks=0 cluster then ks=1 cluster -> no dependent
//   back-to-back MFMAs (dep distance = 2*MI).
//   vmcnt at K-step boundary leaves exactly {A0(s+2),B1(s+2)} in flight
//   => all of step s+1 landed. Stage targets' last ds_read is >=2 barriers
//   before the stage issue (B0: p1; B1: p2; A0: p1-p2; A1: p3).
//   LDS swizzle: row stride 128B; slot' = slot ^ (row&7) -> <=2 lanes/bank
//   (0 SQ_LDS_BANK_CONFLICT measured in rounds 3/5).
// ---------------------------------------------------------------------------
template <int KD, int BMH, int NBt, bool RELU_OUT, int GRID>
__global__ __launch_bounds__(512)
void gemm_8ph(const __bf16* __restrict__ A, const __bf16* __restrict__ Bt,
              const float* __restrict__ bias, void* __restrict__ Cv) {
  constexpr int KT    = KD / 64;       // K-steps
  constexpr int MI    = BMH / 32;      // A fragments per wave per half
  constexpr int AHALF = BMH * 64;      // elems per A half-tile
  constexpr int BHALF = 128 * 64;
  constexpr int ASTEP = 2 * AHALF;
  constexpr int BSTEP = 2 * BHALF;
  constexpr int NDIM  = NBt * 256;
  constexpr int AUL   = BMH / 64;      // gloads per A half-tile per thread

  __shared__ __bf16 lA[2 * ASTEP];
  __shared__ __bf16 lB[2 * BSTEP];

  constexpr int Q = GRID / 8;          // XCD-bijective swizzle (GRID % 8 == 0)
  int bid = blockIdx.x;
  int swb = (bid & 7) * Q + (bid >> 3);
  const int mb = swb / NBt, nb = swb % NBt;
  const long mrow0 = (long)mb * (2 * BMH);
  const int  ncol0 = nb * 256;

  const int tid = threadIdx.x;
  const int wid = tid >> 6, lane = tid & 63;
  const int wr = wid >> 2, wc = wid & 3;     // 2 x 4 wave grid
  const int fl = lane & 15, fh = lane >> 4;

  // ds-read element offsets within a half-tile
  int aoff[MI][2], boff[2][2];
  #pragma unroll
  for (int mi = 0; mi < MI; ++mi)
    #pragma unroll
    for (int ks = 0; ks < 2; ++ks) {
      int row = wr * (BMH / 2) + mi * 16 + fl;
      aoff[mi][ks] = row * 64 + (((ks * 4 + fh) ^ (row & 7)) * 8);
    }
  #pragma unroll
  for (int ni = 0; ni < 2; ++ni)
    #pragma unroll
    for (int ks = 0; ks < 2; ++ks) {
      int row = wc * 32 + ni * 16 + fl;
      boff[ni][ks] = row * 64 + (((ks * 4 + fh) ^ (row & 7)) * 8);
    }

  // Staging source offsets (pre-swizzled source -> linear LDS dest)
  const int r0 = tid >> 3, sl = tid & 7;
  long aS[2][AUL], bS[2][2];
  #pragma unroll
  for (int h = 0; h < 2; ++h) {
    #pragma unroll
    for (int i = 0; i < AUL; ++i) {
      int rr = r0 + i * 64;
      int ss = sl ^ (rr & 7);
      aS[h][i] = (mrow0 + h * BMH + rr) * (long)KD + ss * 8;
    }
    #pragma unroll
    for (int i = 0; i < 2; ++i) {
      int rr = r0 + i * 64;
      int ss = sl ^ (rr & 7);
      bS[h][i] = ((long)(ncol0 + h * 128 + rr)) * KD + ss * 8;
    }
  }
  const int dstw = wid * 512;                // wave-uniform dest chunk (elems)

  auto stA = [&](int h, int t) {
    __bf16* base = lA + (t & 1) * ASTEP + h * AHALF + dstw;
    #pragma unroll
    for (int i = 0; i < AUL; ++i)
      gload_lds16(A + aS[h][i] + (long)t * 64, (void*)(base + i * 4096));
  };
  auto stB = [&](int h, int t) {
    __bf16* base = lB + (t & 1) * BSTEP + h * BHALF + dstw;
    #pragma unroll
    for (int i = 0; i < 2; ++i)
      gload_lds16(Bt + bS[h][i] + (long)t * 64, (void*)(base + i * 4096));
  };

  bf16x8 areg[MI][2], breg0[2][2], breg1[2][2];
  auto loadA = [&](int mh, int s) {
    const __bf16* base = lA + (s & 1) * ASTEP + mh * AHALF;
    #pragma unroll
    for (int mi = 0; mi < MI; ++mi)
      #pragma unroll
      for (int ks = 0; ks < 2; ++ks)
        areg[mi][ks] = *(const bf16x8*)(base + aoff[mi][ks]);
  };
  auto loadB = [&](bf16x8 (&br)[2][2], int nh, int s) {
    const __bf16* base = lB + (s & 1) * BSTEP + nh * BHALF;
    #pragma unroll
    for (int ni = 0; ni < 2; ++ni)
      #pragma unroll
      for (int ks = 0; ks < 2; ++ks)
        br[ni][ks] = *(const bf16x8*)(base + boff[ni][ks]);
  };

  f32x4 acc[2][2][MI][2] = {};

  // ks-outer: all ks=0 MFMAs (independent), then all ks=1 (dep distance 2*MI)
#define PHASE_MFMA(mh, nh, BR)                                                \
  __builtin_amdgcn_s_setprio(1);                                              \
  _Pragma("unroll")                                                           \
  for (int ks = 0; ks < 2; ++ks) {                                            \
    _Pragma("unroll")                                                         \
    for (int mi = 0; mi < MI; ++mi) {                                         \
      _Pragma("unroll")                                                       \
      for (int ni = 0; ni < 2; ++ni)                                          \
        acc[mh][nh][mi][ni] = __builtin_amdgcn_mfma_f32_16x16x32_bf16(        \
            areg[mi][ks], BR[ni][ks], acc[mh][nh][mi][ni], 0, 0, 0);          \
    }                                                                         \
  }                                                                           \
  __builtin_amdgcn_s_setprio(0);

  // Prologue: stage K-steps 0 and 1; wait step 0 (leave step 1 in flight)
  stA(0, 0); stB(0, 0); stA(1, 0); stB(1, 0);
  stA(0, 1); stB(1, 1); stB(0, 1); stA(1, 1);
  if constexpr (BMH == 128) { VMCNT(8); } else { VMCNT(6); }
  __builtin_amdgcn_s_barrier();
  __builtin_amdgcn_sched_barrier(0);

  for (int s = 0; s < KT; ++s) {
    // ---- phase 1: Q(0,0)
    loadA(0, s);
    loadB(breg0, 0, s);
    if (s >= 1 && s + 1 < KT) stB(0, s + 1);
    if constexpr (BMH == 128) LGKM(8);       // 12 reads issued: early drain
    __builtin_amdgcn_s_barrier();
    LGKM(0);
    __builtin_amdgcn_sched_barrier(0);
    PHASE_MFMA(0, 0, breg0);
    __builtin_amdgcn_s_barrier();

    // ---- phase 2: Q(0,1)
    loadB(breg1, 1, s);
    if (s >= 1 && s + 1 < KT) stA(1, s + 1);
    __builtin_amdgcn_s_barrier();
    LGKM(0);
    __builtin_amdgcn_sched_barrier(0);
    PHASE_MFMA(0, 1, breg1);
    __builtin_amdgcn_s_barrier();

    // ---- phase 3: Q(1,1)  (breg1 held)
    loadA(1, s);
    if (s + 2 < KT) stA(0, s + 2);
    __builtin_amdgcn_s_barrier();
    LGKM(0);
    __builtin_amdgcn_sched_barrier(0);
    PHASE_MFMA(1, 1, breg1);
    __builtin_amdgcn_s_barrier();

    // ---- phase 4: Q(1,0)  (areg1 + breg0 held, no ds reads)
    if (s + 2 < KT) stB(1, s + 2);
    __builtin_amdgcn_s_barrier();
    __builtin_amdgcn_sched_barrier(0);
    PHASE_MFMA(1, 0, breg0);
    if (s + 2 < KT) {
      if constexpr (BMH == 128) { VMCNT(4); } else { VMCNT(3); }
    } else {
      VMCNT(0);
    }
    __builtin_amdgcn_s_barrier();
    __builtin_amdgcn_sched_barrier(0);
  }

#undef PHASE_MFMA

  // Epilogue: bias (+relu/cast)
  #pragma unroll
  for (int mh = 0; mh < 2; ++mh)
    #pragma unroll
    for (int nh = 0; nh < 2; ++nh)
      #pragma unroll
      for (int ni = 0; ni < 2; ++ni) {
        int col = ncol0 + nh * 128 + wc * 32 + ni * 16 + fl;
        float bv = bias[col];
        #pragma unroll
        for (int mi = 0; mi < MI; ++mi)
          #pragma unroll
          for (int r = 0; r < 4; ++r) {
            long row = mrow0 + mh * BMH + wr * (BMH / 2) + mi * 16 + fh * 4 + r;
            float v = acc[mh][nh][mi][ni][r] + bv;
            if constexpr (RELU_OUT) {
              v = fmaxf(v, 0.0f);
              ((__bf16*)Cv)[row * NDIM + col] = (__bf16)v;
            } else {
              ((float*)Cv)[row * NDIM + col] = v;
            }
          }
      }
}

// ---------------------------------------------------------------------------
// Fallback 128x128 GEMM (fp32 reg-staged A) -- used only if ws too small
// ---------------------------------------------------------------------------
__device__ __forceinline__ int swz(int row) { return (row >> 1) & 3; }

template <int KD, int NB, bool AF32, bool RELU_OUT>
__global__ __launch_bounds__(256)
void gemm_mfma(const void* __restrict__ A0v, const void* __restrict__ A1v,
               const __bf16* __restrict__ Bt, const float* __restrict__ bias,
               void* __restrict__ Cv) {
  __shared__ __bf16 lA[128 * 32];
  __shared__ __bf16 lB[128 * 32];

  const int total_wg = (M1 / 128) * NB;
  int bid = blockIdx.x;
  const int q = total_wg >> 3;
  int swzb = (bid & 7) * q + (bid >> 3);
  const int mb = swzb / NB, nb = swzb % NB;
  const int mrow0 = mb * 128, ncol0 = nb * 128;
  const int NDIM = NB * 128;

  const int tid = threadIdx.x;
  const int wid = tid >> 6, lane = tid & 63;
  const int wr = wid >> 1, wc = wid & 1;
  const int fl = lane & 15, fh = lane >> 4;

  const float*  Af = nullptr;
  const __bf16* Ab = nullptr;
  if constexpr (AF32) {
    const float* A0 = (const float*)A0v;
    const float* A1 = (const float*)A1v;
    Af = (mrow0 < BATCH) ? (A0 + (size_t)mrow0 * KD)
                         : (A1 + (size_t)(mrow0 - BATCH) * KD);
  } else {
    Ab = (const __bf16*)A0v + (size_t)mrow0 * KD;
  }

  f32x4 acc[4][4] = {};
  const int a_row  = wid * 32 + (lane >> 2);
  const int a_slot = lane & 3;

  const int KT = KD / 32;
  for (int kt = 0; kt < KT; ++kt) {
    f32x4 av[2][2];
    if constexpr (AF32) {
      const float* ap = Af + (size_t)a_row * KD + kt * 32 + a_slot * 8;
      av[0][0] = *(const f32x4*)(ap);
      av[0][1] = *(const f32x4*)(ap + 4);
      av[1][0] = *(const f32x4*)(ap + (size_t)16 * KD);
      av[1][1] = *(const f32x4*)(ap + (size_t)16 * KD + 4);
    }
    __syncthreads();
    {
      int chunk = wid * 2;
      for (int c = 0; c < 2; ++c, ++chunk) {
        int row = chunk * 16 + (lane >> 2);
        int sslot = (lane & 3) ^ swz(row);
        const __bf16* srcp = Bt + (size_t)(ncol0 + row) * KD + kt * 32 + sslot * 8;
        gload_lds16(srcp, (void*)(lB + chunk * 512));
      }
    }
    if constexpr (AF32) {
      for (int r = 0; r < 2; ++r) {
        int row = a_row + r * 16;
        int sslot = a_slot ^ swz(row);
        bf16x8 w;
        for (int j = 0; j < 4; ++j) {
          w[j]     = (__bf16)av[r][0][j];
          w[4 + j] = (__bf16)av[r][1][j];
        }
        *(bf16x8*)(lA + row * 32 + sslot * 8) = w;
      }
    } else {
      int chunk = wid * 2;
      for (int c = 0; c < 2; ++c, ++chunk) {
        int row = chunk * 16 + (lane >> 2);
        int sslot = (lane & 3) ^ swz(row);
        const __bf16* srcp = Ab + (size_t)row * KD + kt * 32 + sslot * 8;
        gload_lds16(srcp, (void*)(lA + chunk * 512));
      }
    }
    __syncthreads();

    bf16x8 afr[4], bfr[4];
    for (int mi = 0; mi < 4; ++mi) {
      int row = wr * 64 + mi * 16 + fl;
      afr[mi] = *(const bf16x8*)(lA + row * 32 + (fh ^ swz(row)) * 8);
    }
    for (int ni = 0; ni < 4; ++ni) {
      int row = wc * 64 + ni * 16 + fl;
      bfr[ni] = *(const bf16x8*)(lB + row * 32 + (fh ^ swz(row)) * 8);
    }
    for (int mi = 0; mi < 4; ++mi)
      for (int ni = 0; ni < 4; ++ni)
        acc[mi][ni] = __builtin_amdgcn_mfma_f32_16x16x32_bf16(
            afr[mi], bfr[ni], acc[mi][ni], 0, 0, 0);
  }

  for (int ni = 0; ni < 4; ++ni) {
    int col = ncol0 + wc * 64 + ni * 16 + fl;
    float bv = bias[col];
    for (int mi = 0; mi < 4; ++mi) {
      for (int r = 0; r < 4; ++r) {
        size_t row = (size_t)mrow0 + wr * 64 + mi * 16 + fh * 4 + r;
        float v = acc[mi][ni][r] + bv;
        if constexpr (RELU_OUT) {
          v = fmaxf(v, 0.0f);
          ((__bf16*)Cv)[row * NDIM + col] = (__bf16)v;
        } else {
          ((float*)Cv)[row * NDIM + col] = v;
        }
      }
    }
  }
}

// ---------------------------------------------------------------------------
// LayerNorm + L2 normalize, in place on X [M1][256] f32. One wave per row.
// ---------------------------------------------------------------------------
__global__ __launch_bounds__(256)
void ln_l2_kernel(float* __restrict__ X, const float* __restrict__ g,
                  const float* __restrict__ be) {
  int row  = blockIdx.x * 4 + (threadIdx.x >> 6);
  int lane = threadIdx.x & 63;
  float* xp = X + (size_t)row * PDIM + lane * 4;
  f32x4 v = *(const f32x4*)xp;

  float s = v[0] + v[1] + v[2] + v[3];
  for (int m = 1; m < 64; m <<= 1) s += __shfl_xor(s, m, 64);
  float mu = s * (1.0f / PDIM);

  f32x4 d;
  for (int j = 0; j < 4; ++j) d[j] = v[j] - mu;
  float qv = dot4(d, d);
  for (int m = 1; m < 64; m <<= 1) qv += __shfl_xor(qv, m, 64);
  float rs = rsqrtf(qv * (1.0f / PDIM) + 1e-5f);

  f32x4 g4 = *(const f32x4*)(g + lane * 4);
  f32x4 b4 = *(const f32x4*)(be + lane * 4);
  f32x4 y;
  for (int j = 0; j < 4; ++j) y[j] = d[j] * rs * g4[j] + b4[j];

  float n2 = dot4(y, y);
  for (int m = 1; m < 64; m <<= 1) n2 += __shfl_xor(n2, m, 64);
  float sc = 1.0f / fmaxf(sqrtf(n2), 1e-12f);
  for (int j = 0; j < 4; ++j) y[j] *= sc;
  *(f32x4*)xp = y;
}

// ---------------------------------------------------------------------------
// Per-row contrastive loss.
// ---------------------------------------------------------------------------
__global__ __launch_bounds__(256)
void loss_kernel(const float* __restrict__ X, const float* __restrict__ negbuf,
                 const int* __restrict__ nidx, float* __restrict__ partials) {
  __shared__ float lsum[4];
  int b    = blockIdx.x * 4 + (threadIdx.x >> 6);
  int lane = threadIdx.x & 63;
  int g = lane >> 4, lg = lane & 15;

  const float* arow = X + (size_t)b * PDIM;
  const float* prow = X + (size_t)(BATCH + b) * PDIM;

  f32x4 a4[4];
  for (int j = 0; j < 4; ++j) a4[j] = *(const f32x4*)(arow + lg * 16 + j * 4);

  float ps = 0.0f;
  for (int j = 0; j < 4; ++j) {
    f32x4 p = *(const f32x4*)(prow + lg * 16 + j * 4);
    ps += dot4(a4[j], p);
  }
  for (int m = 1; m < 16; m <<= 1) ps += __shfl_xor(ps, m, 64);
  float pos = ps * 2.0f;  // /TEMPERATURE

  float myneg = -3.0e38f;
  for (int k4 = 0; k4 < 16; ++k4) {
    int k = k4 * 4 + g;
    int idx = nidx[(size_t)b * KNEG + k];
    const float* nrow = negbuf + (size_t)idx * PDIM;
    float sv = 0.0f;
    for (int j = 0; j < 4; ++j) {
      f32x4 nv = *(const f32x4*)(nrow + lg * 16 + j * 4);
      sv += dot4(a4[j], nv);
    }
    for (int m = 1; m < 16; m <<= 1) sv += __shfl_xor(sv, m, 64);
    if (lg == k4) myneg = sv * 2.0f;
  }

  float mx = myneg;
  for (int m = 1; m < 64; m <<= 1) mx = fmaxf(mx, __shfl_xor(mx, m, 64));
  mx = fmaxf(mx, pos);
  float e = expf(myneg - mx);
  for (int m = 1; m < 64; m <<= 1) e += __shfl_xor(e, m, 64);
  float tot = e + expf(pos - mx);
  float lb = -(pos - mx - logf(tot));

  if (lane == 0) lsum[threadIdx.x >> 6] = lb;
  __syncthreads();
  if (threadIdx.x == 0)
    partials[blockIdx.x] = lsum[0] + lsum[1] + lsum[2] + lsum[3];
}

__global__ void finalize_kernel(const float* __restrict__ partials,
                                float* __restrict__ out) {
  __shared__ float ls[4];
  int tid = threadIdx.x;
  float s = 0.0f;
  for (int i = tid; i < 4096; i += 256) s += partials[i];
  for (int m = 1; m < 64; m <<= 1) s += __shfl_xor(s, m, 64);
  if ((tid & 63) == 0) ls[tid >> 6] = s;
  __syncthreads();
  if (tid == 0) out[0] = (ls[0] + ls[1] + ls[2] + ls[3]) * (1.0f / BATCH);
}

// ---------------------------------------------------------------------------
extern "C" void kernel_launch(void* const* d_in, const int* in_sizes, int n_in,
                              void* d_out, int out_size, void* d_ws, size_t ws_size,
                              hipStream_t stream) {
  const float* hidden   = (const float*)d_in[0];
  const float* positive = (const float*)d_in[1];
  const float* negbuf   = (const float*)d_in[2];
  const float* W1       = (const float*)d_in[3];
  const float* b1       = (const float*)d_in[4];
  const float* W2       = (const float*)d_in[5];
  const float* b2       = (const float*)d_in[6];
  const float* gamma    = (const float*)d_in[7];
  const float* beta     = (const float*)d_in[8];
  const int*   nidx     = (const int*)d_in[9];
  float* out = (float*)d_out;

  char* ws = (char*)d_ws;

  const size_t OFF_Y1   = 134217728;
  const size_t OFF_W1T  = OFF_Y1 + 67108864;
  const size_t OFF_W2T  = OFF_W1T + 4194304;
  const size_t OFF_PART = OFF_W2T + 524288;
  const size_t NEED_BIG = OFF_PART + 16384;

  const bool big = (ws_size >= NEED_BIG);

  __bf16* W1T; __bf16* W2T; __bf16* Y1; float* X; float* partials;
  __bf16* Abf = nullptr;
  if (big) {
    Abf      = (__bf16*)(ws);
    Y1       = (__bf16*)(ws + OFF_Y1);
    W1T      = (__bf16*)(ws + OFF_W1T);
    W2T      = (__bf16*)(ws + OFF_W2T);
    partials = (float*) (ws + OFF_PART);
    X        = (float*) (ws);  // overlaps dead Abf
  } else {
    W1T      = (__bf16*)(ws);
    W2T      = (__bf16*)(ws + 4194304);
    Y1       = (__bf16*)(ws + 4718592);
    X        = (float*) (ws + 71827456);
    partials = (float*) (ws + 105381888);
  }

  transpose_cast_kernel<<<dim3(HHDIM / 32, HDIM / 32), dim3(32, 8), 0, stream>>>(
      W1, W1T, HDIM, HHDIM);
  transpose_cast_kernel<<<dim3(PDIM / 32, HHDIM / 32), dim3(32, 8), 0, stream>>>(
      W2, W2T, HHDIM, PDIM);

  if (big) {
    const long n8 = (long)BATCH * HDIM / 8;
    cast_bf16_kernel<<<2048, 256, 0, stream>>>(hidden, Abf, n8);
    cast_bf16_kernel<<<2048, 256, 0, stream>>>(positive, Abf + (size_t)BATCH * HDIM, n8);

    // GEMM1: [32768,2048] @ [2048,1024]^T + b1, relu -> Y1 (bf16). 256x256 tile.
    gemm_8ph<HDIM, 128, HHDIM / 256, true, (M1 / 256) * (HHDIM / 256)>
        <<<(M1 / 256) * (HHDIM / 256), 512, 0, stream>>>(Abf, W1T, b1, Y1);

    // GEMM2: [32768,1024] @ [1024,256]^T + b2 -> X (f32). 128x256 tile, grid 256.
    gemm_8ph<HHDIM, 64, PDIM / 256, false, (M1 / 128) * (PDIM / 256)>
        <<<(M1 / 128) * (PDIM / 256), 512, 0, stream>>>(Y1, W2T, b2, X);
  } else {
    gemm_mfma<HDIM, HHDIM / 128, true, true>
        <<<(M1 / 128) * (HHDIM / 128), 256, 0, stream>>>(
            hidden, positive, W1T, b1, Y1);
    gemm_mfma<HHDIM, PDIM / 128, false, false>
        <<<(M1 / 128) * (PDIM / 128), 256, 0, stream>>>(
            Y1, nullptr, W2T, b2, X);
  }

  ln_l2_kernel<<<M1 / 4, 256, 0, stream>>>(X, gamma, beta);
  loss_kernel<<<BATCH / 4, 256, 0, stream>>>(X, negbuf, nidx, partials);
  finalize_kernel<<<1, 256, 0, stream>>>(partials, out);
}

// Round 7
// 334.364 us; speedup vs baseline: 1.1723x; 1.0149x over previous
//
#include <hip/hip_runtime.h>
#include <hip/hip_bf16.h>
#include <cstdint>

// Problem constants
#define BATCH   16384
#define HDIM    2048
#define HHDIM   1024
#define PDIM    256
#define KNEG    64
#define NBUF    2000
#define M1      (2 * BATCH)          // 32768 rows through the projection head

typedef float  f32x4  __attribute__((ext_vector_type(4)));
typedef __bf16 bf16x8 __attribute__((ext_vector_type(8)));

typedef __attribute__((address_space(3))) unsigned int       lds_u32;
typedef __attribute__((address_space(1))) const unsigned int glb_u32;

__device__ __forceinline__ void gload_lds16(const void* g, void* l) {
  __builtin_amdgcn_global_load_lds((glb_u32*)g, (lds_u32*)l, 16, 0, 0);
}

__device__ __forceinline__ float dot4(f32x4 a, f32x4 b) {
  return a[0]*b[0] + a[1]*b[1] + a[2]*b[2] + a[3]*b[3];
}

#define VMCNT(n) asm volatile("s_waitcnt vmcnt(" #n ")" ::: "memory")
#define LGKM(n)  asm volatile("s_waitcnt lgkmcnt(" #n ")" ::: "memory")

// ---------------------------------------------------------------------------
// Transpose + cast: src [K][N] f32 row-major  ->  dst [N][K] bf16 row-major
// ---------------------------------------------------------------------------
__global__ void transpose_cast_kernel(const float* __restrict__ src,
                                      __bf16* __restrict__ dst, int K, int N) {
  __shared__ float tile[32][33];
  int bn = blockIdx.x * 32, bk = blockIdx.y * 32;
  int tx = threadIdx.x, ty = threadIdx.y;  // 32 x 8
  for (int j = 0; j < 32; j += 8)
    tile[ty + j][tx] = src[(size_t)(bk + ty + j) * N + bn + tx];
  __syncthreads();
  for (int j = 0; j < 32; j += 8)
    dst[(size_t)(bn + ty + j) * K + bk + tx] = (__bf16)tile[tx][ty + j];
}

// ---------------------------------------------------------------------------
// 8-phase (2*BMH)x256 MFMA GEMM (T2+T3+T4+T5), ks-outer MFMA ordering.
//   C[M][NBt*256] = A[M][KD] @ Bt[NBt*256][KD]^T + bias
//   512 threads = 8 waves (2M x 4N). BK = 64.
//   AF32: A is fp32 (two pointers, anchors/positives, split at row BATCH).
//         A staged via T14 async split: issue global f32 loads one phase
//         early (p1: A1(s+1), p3: A0(s+2)), cvt + swizzled ds_write_b128 the
//         following phase (p2/p4). vmcnt then counts only B's gload_lds:
//         at K-step boundary the A-reg loads are already drained by their
//         cvt, so VMCNT(2) leaves exactly B1(s+2) in flight => B0(s+1)
//         landed. ds_write visibility: writer's LGKM(0) precedes its next
//         barrier; consumer reads are >=3 barriers later.
//   !AF32: A staged via gload_lds like B (r6-verified path).
//   LNFUSE (requires NBt==1): LayerNorm + L2-normalize fused into the
//         epilogue via two cross-wave LDS reductions (rows are complete
//         within the block: 128 rows x 256 cols).
//   LDS swizzle: row stride 128B; slot' = slot ^ (row&7) -> <=2 lanes/bank
//   (0 SQ_LDS_BANK_CONFLICT measured rounds 3/5/6).
// ---------------------------------------------------------------------------
template <int KD, int BMH, int NBt, bool AF32, bool RELU_OUT, bool LNFUSE, int GRID>
__global__ __launch_bounds__(512)
void gemm_8ph(const void* __restrict__ A0v, const void* __restrict__ A1v,
              const __bf16* __restrict__ Bt, const float* __restrict__ bias,
              const float* __restrict__ lng, const float* __restrict__ lnb,
              void* __restrict__ Cv) {
  static_assert(!LNFUSE || NBt == 1, "LN fusion needs full rows per block");
  constexpr int KT    = KD / 64;       // K-steps
  constexpr int MI    = BMH / 32;      // A fragments per wave per half
  constexpr int AHALF = BMH * 64;      // elems per A half-tile
  constexpr int BHALF = 128 * 64;
  constexpr int ASTEP = 2 * AHALF;
  constexpr int BSTEP = 2 * BHALF;
  constexpr int NDIM  = NBt * 256;
  constexpr int AUL   = BMH / 64;      // gloads per A half-tile per thread (!AF32)

  __shared__ __bf16 lA[2 * ASTEP];
  __shared__ __bf16 lB[2 * BSTEP];

  constexpr int Q = GRID / 8;          // XCD-bijective swizzle (GRID % 8 == 0)
  int bid = blockIdx.x;
  int swb = (bid & 7) * Q + (bid >> 3);
  const int mb = swb / NBt, nb = swb % NBt;
  const long mrow0 = (long)mb * (2 * BMH);
  const int  ncol0 = nb * 256;

  const int tid = threadIdx.x;
  const int wid = tid >> 6, lane = tid & 63;
  const int wr = wid >> 2, wc = wid & 3;     // 2 x 4 wave grid
  const int fl = lane & 15, fh = lane >> 4;

  // ds-read element offsets within a half-tile
  int aoff[MI][2], boff[2][2];
  #pragma unroll
  for (int mi = 0; mi < MI; ++mi)
    #pragma unroll
    for (int ks = 0; ks < 2; ++ks) {
      int row = wr * (BMH / 2) + mi * 16 + fl;
      aoff[mi][ks] = row * 64 + (((ks * 4 + fh) ^ (row & 7)) * 8);
    }
  #pragma unroll
  for (int ni = 0; ni < 2; ++ni)
    #pragma unroll
    for (int ks = 0; ks < 2; ++ks) {
      int row = wc * 32 + ni * 16 + fl;
      boff[ni][ks] = row * 64 + (((ks * 4 + fh) ^ (row & 7)) * 8);
    }

  // ---- B staging (gload_lds, pre-swizzled source -> linear LDS dest)
  const int r0 = tid >> 3, sl = tid & 7;
  long bS[2][2];
  #pragma unroll
  for (int h = 0; h < 2; ++h)
    #pragma unroll
    for (int i = 0; i < 2; ++i) {
      int rr = r0 + i * 64;
      int ss = sl ^ (rr & 7);
      bS[h][i] = ((long)(ncol0 + h * 128 + rr)) * KD + ss * 8;
    }
  const int dstw = wid * 512;                // wave-uniform dest chunk (elems)

  auto stB = [&](int h, int t) {
    __bf16* base = lB + (t & 1) * BSTEP + h * BHALF + dstw;
    #pragma unroll
    for (int i = 0; i < 2; ++i)
      gload_lds16(Bt + bS[h][i] + (long)t * 64, (void*)(base + i * 4096));
  };

  // ---- A staging: either gload_lds (bf16 A) or f32 reg-stage (AF32)
  long aS[2][AUL];
  const float* Afp = nullptr;
  if constexpr (AF32) {
    const float* A0 = (const float*)A0v;
    const float* A1 = (const float*)A1v;
    Afp = (mrow0 < BATCH) ? (A0 + (size_t)mrow0 * KD)
                          : (A1 + (size_t)(mrow0 - BATCH) * KD);
  } else {
    #pragma unroll
    for (int h = 0; h < 2; ++h)
      #pragma unroll
      for (int i = 0; i < AUL; ++i) {
        int rr = r0 + i * 64;
        int ss = sl ^ (rr & 7);
        aS[h][i] = (mrow0 + h * BMH + rr) * (long)KD + ss * 8;
      }
  }

  auto stA = [&](int h, int t) {    // !AF32 path
    __bf16* base = lA + (t & 1) * ASTEP + h * AHALF + dstw;
    #pragma unroll
    for (int i = 0; i < AUL; ++i)
      gload_lds16((const __bf16*)A0v + aS[h][i] + (long)t * 64,
                  (void*)(base + i * 4096));
  };

  // AF32 path: thread covers row rowA = tid>>2, slot pair p = tid&3
  const int rowA = tid >> 2, pA = tid & 3;
  f32x4 aq[4];                               // in-flight f32 A data
  auto issueA = [&](int h, int t) {          // issue 4 dwordx4 -> regs
    const float* p = Afp + (size_t)(h * 128 + rowA) * KD + t * 64 + pA * 16;
    aq[0] = *(const f32x4*)(p);
    aq[1] = *(const f32x4*)(p + 4);
    aq[2] = *(const f32x4*)(p + 8);
    aq[3] = *(const f32x4*)(p + 12);
  };
  auto writeA = [&](int h, int t) {          // cvt + swizzled ds_write
    bf16x8 w0, w1;
    #pragma unroll
    for (int j = 0; j < 4; ++j) {
      w0[j] = (__bf16)aq[0][j]; w0[4 + j] = (__bf16)aq[1][j];
      w1[j] = (__bf16)aq[2][j]; w1[4 + j] = (__bf16)aq[3][j];
    }
    __bf16* base = lA + (t & 1) * ASTEP + h * AHALF + rowA * 64;
    *(bf16x8*)(base + (((2 * pA)     ^ (rowA & 7)) * 8)) = w0;
    *(bf16x8*)(base + (((2 * pA + 1) ^ (rowA & 7)) * 8)) = w1;
  };

  bf16x8 areg[MI][2], breg0[2][2], breg1[2][2];
  auto loadA = [&](int mh, int s) {
    const __bf16* base = lA + (s & 1) * ASTEP + mh * AHALF;
    #pragma unroll
    for (int mi = 0; mi < MI; ++mi)
      #pragma unroll
      for (int ks = 0; ks < 2; ++ks)
        areg[mi][ks] = *(const bf16x8*)(base + aoff[mi][ks]);
  };
  auto loadB = [&](bf16x8 (&br)[2][2], int nh, int s) {
    const __bf16* base = lB + (s & 1) * BSTEP + nh * BHALF;
    #pragma unroll
    for (int ni = 0; ni < 2; ++ni)
      #pragma unroll
      for (int ks = 0; ks < 2; ++ks)
        br[ni][ks] = *(const bf16x8*)(base + boff[ni][ks]);
  };

  f32x4 acc[2][2][MI][2] = {};

  // ks-outer: all ks=0 MFMAs (independent), then all ks=1 (dep distance 2*MI)
#define PHASE_MFMA(mh, nh, BR)                                                \
  __builtin_amdgcn_s_setprio(1);                                              \
  _Pragma("unroll")                                                           \
  for (int ks = 0; ks < 2; ++ks) {                                            \
    _Pragma("unroll")                                                         \
    for (int mi = 0; mi < MI; ++mi) {                                         \
      _Pragma("unroll")                                                       \
      for (int ni = 0; ni < 2; ++ni)                                          \
        acc[mh][nh][mi][ni] = __builtin_amdgcn_mfma_f32_16x16x32_bf16(        \
            areg[mi][ks], BR[ni][ks], acc[mh][nh][mi][ni], 0, 0, 0);          \
    }                                                                         \
  }                                                                           \
  __builtin_amdgcn_s_setprio(0);

  // Prologue: stage K-steps 0 and 1; leave step-1 B in flight
  if constexpr (AF32) {
    issueA(0, 0); writeA(0, 0);
    issueA(1, 0); writeA(1, 0);
    issueA(0, 1); writeA(0, 1);
    issueA(1, 1); writeA(1, 1);
  } else {
    stA(0, 0); stA(1, 0); stA(0, 1); stA(1, 1);
  }
  stB(0, 0); stB(1, 0); stB(0, 1); stB(1, 1);
  if constexpr (AF32)           { VMCNT(4); LGKM(0); }
  else if constexpr (BMH == 128){ VMCNT(8); }
  else                          { VMCNT(6); }
  __builtin_amdgcn_s_barrier();
  __builtin_amdgcn_sched_barrier(0);

  for (int s = 0; s < KT; ++s) {
    // ---- phase 1: Q(0,0); prefetch-issue A1(s+1) (AF32), stage B0(s+1)
    loadA(0, s);
    loadB(breg0, 0, s);
    if constexpr (AF32) { if (s >= 1 && s + 1 < KT) issueA(1, s + 1); }
    if (s >= 1 && s + 1 < KT) stB(0, s + 1);
    if constexpr (BMH == 128) LGKM(8);       // 12 ds_reads issued: early drain
    __builtin_amdgcn_s_barrier();
    LGKM(0);
    __builtin_amdgcn_sched_barrier(0);
    PHASE_MFMA(0, 0, breg0);
    __builtin_amdgcn_s_barrier();

    // ---- phase 2: Q(0,1); land A1(s+1)
    loadB(breg1, 1, s);
    if constexpr (AF32) { if (s >= 1 && s + 1 < KT) writeA(1, s + 1); }
    else                { if (s >= 1 && s + 1 < KT) stA(1, s + 1); }
    __builtin_amdgcn_s_barrier();
    LGKM(0);
    __builtin_amdgcn_sched_barrier(0);
    PHASE_MFMA(0, 1, breg1);
    __builtin_amdgcn_s_barrier();

    // ---- phase 3: Q(1,1)  (breg1 held); prefetch-issue A0(s+2)
    loadA(1, s);
    if constexpr (AF32) { if (s + 2 < KT) issueA(0, s + 2); }
    else                { if (s + 2 < KT) stA(0, s + 2); }
    __builtin_amdgcn_s_barrier();
    LGKM(0);
    __builtin_amdgcn_sched_barrier(0);
    PHASE_MFMA(1, 1, breg1);
    __builtin_amdgcn_s_barrier();

    // ---- phase 4: Q(1,0)  (areg1 + breg0 held); land A0(s+2), stage B1(s+2)
    if constexpr (AF32) { if (s + 2 < KT) writeA(0, s + 2); }
    if (s + 2 < KT) stB(1, s + 2);
    __builtin_amdgcn_s_barrier();
    LGKM(0);                                  // drains p4 ds_writes (AF32)
    __builtin_amdgcn_sched_barrier(0);
    PHASE_MFMA(1, 0, breg0);
    if (s + 2 < KT) {
      if constexpr (AF32)            { VMCNT(2); }
      else if constexpr (BMH == 128) { VMCNT(4); }
      else                           { VMCNT(3); }
    } else {
      VMCNT(0);
    }
    __builtin_amdgcn_s_barrier();
    __builtin_amdgcn_sched_barrier(0);
  }

#undef PHASE_MFMA

  if constexpr (LNFUSE) {
    // ---- Fused bias + LayerNorm + L2-normalize epilogue (rows complete).
    // Scratch overlays lA (K-loop reads all drained by final barrier).
    float (*s1p)[4] = (float(*)[4])((float*)lA);
    float (*s2p)[4] = (float(*)[4])((float*)lA + 512);
    float (*n2p)[4] = (float(*)[4])((float*)lA + 1024);

    float v[2][2][MI][2][4];
    float gg[2][2], bb[2][2];
    #pragma unroll
    for (int nh = 0; nh < 2; ++nh)
      #pragma unroll
      for (int ni = 0; ni < 2; ++ni) {
        int c = nh * 128 + wc * 32 + ni * 16 + fl;
        float bv = bias[c];
        gg[nh][ni] = lng[c]; bb[nh][ni] = lnb[c];
        #pragma unroll
        for (int mh = 0; mh < 2; ++mh)
          #pragma unroll
          for (int mi = 0; mi < MI; ++mi)
            #pragma unroll
            for (int r = 0; r < 4; ++r)
              v[mh][nh][mi][ni][r] = acc[mh][nh][mi][ni][r] + bv;
      }

    // per-row sum / sumsq partials -> fl-group shfl reduce -> LDS over wc
    #pragma unroll
    for (int mh = 0; mh < 2; ++mh)
      #pragma unroll
      for (int mi = 0; mi < MI; ++mi)
        #pragma unroll
        for (int r = 0; r < 4; ++r) {
          float s1 = 0.0f, s2 = 0.0f;
          #pragma unroll
          for (int nh = 0; nh < 2; ++nh)
            #pragma unroll
            for (int ni = 0; ni < 2; ++ni) {
              float x = v[mh][nh][mi][ni][r];
              s1 += x; s2 += x * x;
            }
          for (int m = 1; m < 16; m <<= 1) {
            s1 += __shfl_xor(s1, m, 64);
            s2 += __shfl_xor(s2, m, 64);
          }
          if (fl == 0) {
            int lr = mh * 64 + wr * 32 + mi * 16 + fh * 4 + r;
            s1p[lr][wc] = s1; s2p[lr][wc] = s2;
          }
        }
    __syncthreads();

    float n2loc[2][MI][4];
    #pragma unroll
    for (int mh = 0; mh < 2; ++mh)
      #pragma unroll
      for (int mi = 0; mi < MI; ++mi)
        #pragma unroll
        for (int r = 0; r < 4; ++r) {
          int lr = mh * 64 + wr * 32 + mi * 16 + fh * 4 + r;
          float t1 = s1p[lr][0] + s1p[lr][1] + s1p[lr][2] + s1p[lr][3];
          float t2 = s2p[lr][0] + s2p[lr][1] + s2p[lr][2] + s2p[lr][3];
          float mu = t1 * (1.0f / PDIM);
          float var = t2 * (1.0f / PDIM) - mu * mu;
          float rstd = rsqrtf(var + 1e-5f);
          float n2 = 0.0f;
          #pragma unroll
          for (int nh = 0; nh < 2; ++nh)
            #pragma unroll
            for (int ni = 0; ni < 2; ++ni) {
              float y = (v[mh][nh][mi][ni][r] - mu) * rstd * gg[nh][ni] + bb[nh][ni];
              v[mh][nh][mi][ni][r] = y;
              n2 += y * y;
            }
          for (int m = 1; m < 16; m <<= 1) n2 += __shfl_xor(n2, m, 64);
          n2loc[mh][mi][r] = n2;
        }
    #pragma unroll
    for (int mh = 0; mh < 2; ++mh)
      #pragma unroll
      for (int mi = 0; mi < MI; ++mi)
        #pragma unroll
        for (int r = 0; r < 4; ++r)
          if (fl == 0) {
            int lr = mh * 64 + wr * 32 + mi * 16 + fh * 4 + r;
            n2p[lr][wc] = n2loc[mh][mi][r];
          }
    __syncthreads();

    #pragma unroll
    for (int mh = 0; mh < 2; ++mh)
      #pragma unroll
      for (int mi = 0; mi < MI; ++mi)
        #pragma unroll
        for (int r = 0; r < 4; ++r) {
          int lr = mh * 64 + wr * 32 + mi * 16 + fh * 4 + r;
          float t = n2p[lr][0] + n2p[lr][1] + n2p[lr][2] + n2p[lr][3];
          float sc = 1.0f / fmaxf(sqrtf(t), 1e-12f);
          #pragma unroll
          for (int nh = 0; nh < 2; ++nh)
            #pragma unroll
            for (int ni = 0; ni < 2; ++ni) {
              int c = nh * 128 + wc * 32 + ni * 16 + fl;
              ((float*)Cv)[(mrow0 + lr) * NDIM + c] = v[mh][nh][mi][ni][r] * sc;
            }
        }
  } else {
    // ---- plain epilogue: bias (+relu/cast)
    #pragma unroll
    for (int mh = 0; mh < 2; ++mh)
      #pragma unroll
      for (int nh = 0; nh < 2; ++nh)
        #pragma unroll
        for (int ni = 0; ni < 2; ++ni) {
          int col = ncol0 + nh * 128 + wc * 32 + ni * 16 + fl;
          float bv = bias[col];
          #pragma unroll
          for (int mi = 0; mi < MI; ++mi)
            #pragma unroll
            for (int r = 0; r < 4; ++r) {
              long row = mrow0 + mh * BMH + wr * (BMH / 2) + mi * 16 + fh * 4 + r;
              float x = acc[mh][nh][mi][ni][r] + bv;
              if constexpr (RELU_OUT) {
                x = fmaxf(x, 0.0f);
                ((__bf16*)Cv)[row * NDIM + col] = (__bf16)x;
              } else {
                ((float*)Cv)[row * NDIM + col] = x;
              }
            }
        }
  }
}

// ---------------------------------------------------------------------------
// Per-row contrastive loss. One wave per row; 16-lane groups handle 4 negs
// at a time; each lane ends holding one neg logit; butterfly softmax.
// ---------------------------------------------------------------------------
__global__ __launch_bounds__(256)
void loss_kernel(const float* __restrict__ X, const float* __restrict__ negbuf,
                 const int* __restrict__ nidx, float* __restrict__ partials) {
  __shared__ float lsum[4];
  int b    = blockIdx.x * 4 + (threadIdx.x >> 6);
  int lane = threadIdx.x & 63;
  int g = lane >> 4, lg = lane & 15;

  const float* arow = X + (size_t)b * PDIM;
  const float* prow = X + (size_t)(BATCH + b) * PDIM;

  f32x4 a4[4];
  for (int j = 0; j < 4; ++j) a4[j] = *(const f32x4*)(arow + lg * 16 + j * 4);

  float ps = 0.0f;
  for (int j = 0; j < 4; ++j) {
    f32x4 p = *(const f32x4*)(prow + lg * 16 + j * 4);
    ps += dot4(a4[j], p);
  }
  for (int m = 1; m < 16; m <<= 1) ps += __shfl_xor(ps, m, 64);
  float pos = ps * 2.0f;  // /TEMPERATURE

  float myneg = -3.0e38f;
  for (int k4 = 0; k4 < 16; ++k4) {
    int k = k4 * 4 + g;
    int idx = nidx[(size_t)b * KNEG + k];
    const float* nrow = negbuf + (size_t)idx * PDIM;
    float sv = 0.0f;
    for (int j = 0; j < 4; ++j) {
      f32x4 nv = *(const f32x4*)(nrow + lg * 16 + j * 4);
      sv += dot4(a4[j], nv);
    }
    for (int m = 1; m < 16; m <<= 1) sv += __shfl_xor(sv, m, 64);
    if (lg == k4) myneg = sv * 2.0f;
  }

  float mx = myneg;
  for (int m = 1; m < 64; m <<= 1) mx = fmaxf(mx, __shfl_xor(mx, m, 64));
  mx = fmaxf(mx, pos);
  float e = expf(myneg - mx);
  for (int m = 1; m < 64; m <<= 1) e += __shfl_xor(e, m, 64);
  float tot = e + expf(pos - mx);
  float lb = -(pos - mx - logf(tot));

  if (lane == 0) lsum[threadIdx.x >> 6] = lb;
  __syncthreads();
  if (threadIdx.x == 0)
    partials[blockIdx.x] = lsum[0] + lsum[1] + lsum[2] + lsum[3];
}

__global__ void finalize_kernel(const float* __restrict__ partials,
                                float* __restrict__ out) {
  __shared__ float ls[4];
  int tid = threadIdx.x;
  float s = 0.0f;
  for (int i = tid; i < 4096; i += 256) s += partials[i];
  for (int m = 1; m < 64; m <<= 1) s += __shfl_xor(s, m, 64);
  if ((tid & 63) == 0) ls[tid >> 6] = s;
  __syncthreads();
  if (tid == 0) out[0] = (ls[0] + ls[1] + ls[2] + ls[3]) * (1.0f / BATCH);
}

// ---------------------------------------------------------------------------
extern "C" void kernel_launch(void* const* d_in, const int* in_sizes, int n_in,
                              void* d_out, int out_size, void* d_ws, size_t ws_size,
                              hipStream_t stream) {
  const float* hidden   = (const float*)d_in[0];
  const float* positive = (const float*)d_in[1];
  const float* negbuf   = (const float*)d_in[2];
  const float* W1       = (const float*)d_in[3];
  const float* b1       = (const float*)d_in[4];
  const float* W2       = (const float*)d_in[5];
  const float* b2       = (const float*)d_in[6];
  const float* gamma    = (const float*)d_in[7];
  const float* beta     = (const float*)d_in[8];
  const int*   nidx     = (const int*)d_in[9];
  float* out = (float*)d_out;

  char* ws = (char*)d_ws;
  // Layout (~100.6 MiB):
  //   W1T [1024][2048] bf16 @ 0        (4 MiB)
  //   W2T [256][1024]  bf16 @ 4 MiB    (0.5 MiB)
  //   Y1  [32768][1024] bf16 @ 4.5 MiB (64 MiB)
  //   X   [32768][256]  f32            (32 MiB)
  //   partials [4096]   f32            (16 KiB)
  __bf16* W1T      = (__bf16*)(ws);
  __bf16* W2T      = (__bf16*)(ws + 4194304);
  __bf16* Y1       = (__bf16*)(ws + 4718592);
  float*  X        = (float*) (ws + 71827456);
  float*  partials = (float*) (ws + 105381888);

  transpose_cast_kernel<<<dim3(HHDIM / 32, HDIM / 32), dim3(32, 8), 0, stream>>>(
      W1, W1T, HDIM, HHDIM);
  transpose_cast_kernel<<<dim3(PDIM / 32, HHDIM / 32), dim3(32, 8), 0, stream>>>(
      W2, W2T, HHDIM, PDIM);

  // GEMM1: fp32 A (hidden|positive) @ W1T^T + b1, relu -> Y1 (bf16).
  // 256x256 tile, fused f32->bf16 staging (no separate cast kernels).
  gemm_8ph<HDIM, 128, HHDIM / 256, true, true, false, (M1 / 256) * (HHDIM / 256)>
      <<<(M1 / 256) * (HHDIM / 256), 512, 0, stream>>>(
          hidden, positive, W1T, b1, nullptr, nullptr, Y1);

  // GEMM2: Y1 @ W2T^T + b2, fused LayerNorm + L2-normalize -> X (f32).
  // 128x256 tile, grid 256.
  gemm_8ph<HHDIM, 64, PDIM / 256, false, false, true, (M1 / 128) * (PDIM / 256)>
      <<<(M1 / 128) * (PDIM / 256), 512, 0, stream>>>(
          Y1, nullptr, W2T, b2, gamma, beta, X);

  loss_kernel<<<BATCH / 4, 256, 0, stream>>>(X, negbuf, nidx, partials);
  finalize_kernel<<<1, 256, 0, stream>>>(partials, out);
}

// Round 8
// 303.222 us; speedup vs baseline: 1.2927x; 1.1027x over previous
//
#include <hip/hip_runtime.h>
#include <hip/hip_bf16.h>
#include <cstdint>

// Problem constants
#define BATCH   16384
#define HDIM    2048
#define HHDIM   1024
#define PDIM    256
#define KNEG    64
#define NBUF    2000
#define M1      (2 * BATCH)          // 32768 rows through the projection head

typedef float  f32x4  __attribute__((ext_vector_type(4)));
typedef __bf16 bf16x8 __attribute__((ext_vector_type(8)));

typedef __attribute__((address_space(3))) unsigned int       lds_u32;
typedef __attribute__((address_space(1))) const unsigned int glb_u32;

__device__ __forceinline__ void gload_lds16(const void* g, void* l) {
  __builtin_amdgcn_global_load_lds((glb_u32*)g, (lds_u32*)l, 16, 0, 0);
}

__device__ __forceinline__ float dot4(f32x4 a, f32x4 b) {
  return a[0]*b[0] + a[1]*b[1] + a[2]*b[2] + a[3]*b[3];
}

#define VMCNT(n) asm volatile("s_waitcnt vmcnt(" #n ")" ::: "memory")
#define LGKM(n)  asm volatile("s_waitcnt lgkmcnt(" #n ")" ::: "memory")

// ---------------------------------------------------------------------------
// f32 -> bf16 cast, 8 elems/thread, grid-stride
// ---------------------------------------------------------------------------
__global__ __launch_bounds__(256)
void cast_bf16_kernel(const float* __restrict__ src, __bf16* __restrict__ dst,
                      long n8) {
  long i = (long)blockIdx.x * blockDim.x + threadIdx.x;
  long stride = (long)gridDim.x * blockDim.x;
  for (; i < n8; i += stride) {
    f32x4 a = ((const f32x4*)src)[2 * i];
    f32x4 b = ((const f32x4*)src)[2 * i + 1];
    bf16x8 w;
    for (int j = 0; j < 4; ++j) { w[j] = (__bf16)a[j]; w[4 + j] = (__bf16)b[j]; }
    ((bf16x8*)dst)[i] = w;
  }
}

// ---------------------------------------------------------------------------
// Transpose + cast: src [K][N] f32 row-major  ->  dst [N][K] bf16 row-major
// ---------------------------------------------------------------------------
__global__ void transpose_cast_kernel(const float* __restrict__ src,
                                      __bf16* __restrict__ dst, int K, int N) {
  __shared__ float tile[32][33];
  int bn = blockIdx.x * 32, bk = blockIdx.y * 32;
  int tx = threadIdx.x, ty = threadIdx.y;  // 32 x 8
  for (int j = 0; j < 32; j += 8)
    tile[ty + j][tx] = src[(size_t)(bk + ty + j) * N + bn + tx];
  __syncthreads();
  for (int j = 0; j < 32; j += 8)
    dst[(size_t)(bn + ty + j) * K + bk + tx] = (__bf16)tile[tx][ty + j];
}

// ---------------------------------------------------------------------------
// 8-phase (2*BMH)x256 MFMA GEMM (T2+T3+T4+T5), ks-outer MFMA ordering.
//   C[M][NBt*256] = A[M][KD] @ Bt[NBt*256][KD]^T + bias
//   512 threads = 8 waves (2M x 4N). BK = 64. A (bf16) and B staged via
//   gload_lds with pre-swizzled source. Counted vmcnt at K-step boundary
//   leaves exactly {A0(s+2), B1(s+2)} in flight => step s+1 landed.
//   LNFUSE (requires NBt==1): LayerNorm + L2-normalize fused into the
//   epilogue via two cross-wave LDS reductions (rows complete in block).
//   LDS swizzle: row stride 128B; slot' = slot ^ (row&7) -> <=2 lanes/bank
//   (0 SQ_LDS_BANK_CONFLICT measured rounds 3/5/6/7).
// ---------------------------------------------------------------------------
template <int KD, int BMH, int NBt, bool RELU_OUT, bool LNFUSE, int GRID>
__global__ __launch_bounds__(512)
void gemm_8ph(const __bf16* __restrict__ A, const __bf16* __restrict__ Bt,
              const float* __restrict__ bias,
              const float* __restrict__ lng, const float* __restrict__ lnb,
              void* __restrict__ Cv) {
  static_assert(!LNFUSE || NBt == 1, "LN fusion needs full rows per block");
  constexpr int KT    = KD / 64;       // K-steps
  constexpr int MI    = BMH / 32;      // A fragments per wave per half
  constexpr int AHALF = BMH * 64;      // elems per A half-tile
  constexpr int BHALF = 128 * 64;
  constexpr int ASTEP = 2 * AHALF;
  constexpr int BSTEP = 2 * BHALF;
  constexpr int NDIM  = NBt * 256;
  constexpr int AUL   = BMH / 64;      // gloads per A half-tile per thread

  __shared__ __bf16 lA[2 * ASTEP];
  __shared__ __bf16 lB[2 * BSTEP];

  constexpr int Q = GRID / 8;          // XCD-bijective swizzle (GRID % 8 == 0)
  int bid = blockIdx.x;
  int swb = (bid & 7) * Q + (bid >> 3);
  const int mb = swb / NBt, nb = swb % NBt;
  const long mrow0 = (long)mb * (2 * BMH);
  const int  ncol0 = nb * 256;

  const int tid = threadIdx.x;
  const int wid = tid >> 6, lane = tid & 63;
  const int wr = wid >> 2, wc = wid & 3;     // 2 x 4 wave grid
  const int fl = lane & 15, fh = lane >> 4;

  // ds-read element offsets within a half-tile
  int aoff[MI][2], boff[2][2];
  #pragma unroll
  for (int mi = 0; mi < MI; ++mi)
    #pragma unroll
    for (int ks = 0; ks < 2; ++ks) {
      int row = wr * (BMH / 2) + mi * 16 + fl;
      aoff[mi][ks] = row * 64 + (((ks * 4 + fh) ^ (row & 7)) * 8);
    }
  #pragma unroll
  for (int ni = 0; ni < 2; ++ni)
    #pragma unroll
    for (int ks = 0; ks < 2; ++ks) {
      int row = wc * 32 + ni * 16 + fl;
      boff[ni][ks] = row * 64 + (((ks * 4 + fh) ^ (row & 7)) * 8);
    }

  // Staging source offsets (pre-swizzled source -> linear LDS dest)
  const int r0 = tid >> 3, sl = tid & 7;
  long aS[2][AUL], bS[2][2];
  #pragma unroll
  for (int h = 0; h < 2; ++h) {
    #pragma unroll
    for (int i = 0; i < AUL; ++i) {
      int rr = r0 + i * 64;
      int ss = sl ^ (rr & 7);
      aS[h][i] = (mrow0 + h * BMH + rr) * (long)KD + ss * 8;
    }
    #pragma unroll
    for (int i = 0; i < 2; ++i) {
      int rr = r0 + i * 64;
      int ss = sl ^ (rr & 7);
      bS[h][i] = ((long)(ncol0 + h * 128 + rr)) * KD + ss * 8;
    }
  }
  const int dstw = wid * 512;                // wave-uniform dest chunk (elems)

  auto stA = [&](int h, int t) {
    __bf16* base = lA + (t & 1) * ASTEP + h * AHALF + dstw;
    #pragma unroll
    for (int i = 0; i < AUL; ++i)
      gload_lds16(A + aS[h][i] + (long)t * 64, (void*)(base + i * 4096));
  };
  auto stB = [&](int h, int t) {
    __bf16* base = lB + (t & 1) * BSTEP + h * BHALF + dstw;
    #pragma unroll
    for (int i = 0; i < 2; ++i)
      gload_lds16(Bt + bS[h][i] + (long)t * 64, (void*)(base + i * 4096));
  };

  bf16x8 areg[MI][2], breg0[2][2], breg1[2][2];
  auto loadA = [&](int mh, int s) {
    const __bf16* base = lA + (s & 1) * ASTEP + mh * AHALF;
    #pragma unroll
    for (int mi = 0; mi < MI; ++mi)
      #pragma unroll
      for (int ks = 0; ks < 2; ++ks)
        areg[mi][ks] = *(const bf16x8*)(base + aoff[mi][ks]);
  };
  auto loadB = [&](bf16x8 (&br)[2][2], int nh, int s) {
    const __bf16* base = lB + (s & 1) * BSTEP + nh * BHALF;
    #pragma unroll
    for (int ni = 0; ni < 2; ++ni)
      #pragma unroll
      for (int ks = 0; ks < 2; ++ks)
        br[ni][ks] = *(const bf16x8*)(base + boff[ni][ks]);
  };

  f32x4 acc[2][2][MI][2] = {};

  // ks-outer: all ks=0 MFMAs (independent), then all ks=1 (dep distance 2*MI)
#define PHASE_MFMA(mh, nh, BR)                                                \
  __builtin_amdgcn_s_setprio(1);                                              \
  _Pragma("unroll")                                                           \
  for (int ks = 0; ks < 2; ++ks) {                                            \
    _Pragma("unroll")                                                         \
    for (int mi = 0; mi < MI; ++mi) {                                         \
      _Pragma("unroll")                                                       \
      for (int ni = 0; ni < 2; ++ni)                                          \
        acc[mh][nh][mi][ni] = __builtin_amdgcn_mfma_f32_16x16x32_bf16(        \
            areg[mi][ks], BR[ni][ks], acc[mh][nh][mi][ni], 0, 0, 0);          \
    }                                                                         \
  }                                                                           \
  __builtin_amdgcn_s_setprio(0);

  // Prologue: stage K-steps 0 and 1; wait step 0 (leave step 1 in flight)
  stA(0, 0); stB(0, 0); stA(1, 0); stB(1, 0);
  stA(0, 1); stB(1, 1); stB(0, 1); stA(1, 1);
  if constexpr (BMH == 128) { VMCNT(8); } else { VMCNT(6); }
  __builtin_amdgcn_s_barrier();
  __builtin_amdgcn_sched_barrier(0);

  for (int s = 0; s < KT; ++s) {
    // ---- phase 1: Q(0,0)
    loadA(0, s);
    loadB(breg0, 0, s);
    if (s >= 1 && s + 1 < KT) stB(0, s + 1);
    if constexpr (BMH == 128) LGKM(8);       // 12 ds_reads issued: early drain
    __builtin_amdgcn_s_barrier();
    LGKM(0);
    __builtin_amdgcn_sched_barrier(0);
    PHASE_MFMA(0, 0, breg0);
    __builtin_amdgcn_s_barrier();

    // ---- phase 2: Q(0,1)
    loadB(breg1, 1, s);
    if (s >= 1 && s + 1 < KT) stA(1, s + 1);
    __builtin_amdgcn_s_barrier();
    LGKM(0);
    __builtin_amdgcn_sched_barrier(0);
    PHASE_MFMA(0, 1, breg1);
    __builtin_amdgcn_s_barrier();

    // ---- phase 3: Q(1,1)  (breg1 held)
    loadA(1, s);
    if (s + 2 < KT) stA(0, s + 2);
    __builtin_amdgcn_s_barrier();
    LGKM(0);
    __builtin_amdgcn_sched_barrier(0);
    PHASE_MFMA(1, 1, breg1);
    __builtin_amdgcn_s_barrier();

    // ---- phase 4: Q(1,0)  (areg1 + breg0 held, no ds reads)
    if (s + 2 < KT) stB(1, s + 2);
    __builtin_amdgcn_s_barrier();
    __builtin_amdgcn_sched_barrier(0);
    PHASE_MFMA(1, 0, breg0);
    if (s + 2 < KT) {
      if constexpr (BMH == 128) { VMCNT(4); } else { VMCNT(3); }
    } else {
      VMCNT(0);
    }
    __builtin_amdgcn_s_barrier();
    __builtin_amdgcn_sched_barrier(0);
  }

#undef PHASE_MFMA

  if constexpr (LNFUSE) {
    // ---- Fused bias + LayerNorm + L2-normalize epilogue (rows complete).
    // Scratch overlays lA (K-loop reads all drained by final barrier).
    float (*s1p)[4] = (float(*)[4])((float*)lA);
    float (*s2p)[4] = (float(*)[4])((float*)lA + 512);
    float (*n2p)[4] = (float(*)[4])((float*)lA + 1024);

    float v[2][2][MI][2][4];
    float gg[2][2], bb[2][2];
    #pragma unroll
    for (int nh = 0; nh < 2; ++nh)
      #pragma unroll
      for (int ni = 0; ni < 2; ++ni) {
        int c = nh * 128 + wc * 32 + ni * 16 + fl;
        float bv = bias[c];
        gg[nh][ni] = lng[c]; bb[nh][ni] = lnb[c];
        #pragma unroll
        for (int mh = 0; mh < 2; ++mh)
          #pragma unroll
          for (int mi = 0; mi < MI; ++mi)
            #pragma unroll
            for (int r = 0; r < 4; ++r)
              v[mh][nh][mi][ni][r] = acc[mh][nh][mi][ni][r] + bv;
      }

    // per-row sum / sumsq partials -> fl-group shfl reduce -> LDS over wc
    #pragma unroll
    for (int mh = 0; mh < 2; ++mh)
      #pragma unroll
      for (int mi = 0; mi < MI; ++mi)
        #pragma unroll
        for (int r = 0; r < 4; ++r) {
          float s1 = 0.0f, s2 = 0.0f;
          #pragma unroll
          for (int nh = 0; nh < 2; ++nh)
            #pragma unroll
            for (int ni = 0; ni < 2; ++ni) {
              float x = v[mh][nh][mi][ni][r];
              s1 += x; s2 += x * x;
            }
          for (int m = 1; m < 16; m <<= 1) {
            s1 += __shfl_xor(s1, m, 64);
            s2 += __shfl_xor(s2, m, 64);
          }
          if (fl == 0) {
            int lr = mh * 64 + wr * 32 + mi * 16 + fh * 4 + r;
            s1p[lr][wc] = s1; s2p[lr][wc] = s2;
          }
        }
    __syncthreads();

    float n2loc[2][MI][4];
    #pragma unroll
    for (int mh = 0; mh < 2; ++mh)
      #pragma unroll
      for (int mi = 0; mi < MI; ++mi)
        #pragma unroll
        for (int r = 0; r < 4; ++r) {
          int lr = mh * 64 + wr * 32 + mi * 16 + fh * 4 + r;
          float t1 = s1p[lr][0] + s1p[lr][1] + s1p[lr][2] + s1p[lr][3];
          float t2 = s2p[lr][0] + s2p[lr][1] + s2p[lr][2] + s2p[lr][3];
          float mu = t1 * (1.0f / PDIM);
          float var = t2 * (1.0f / PDIM) - mu * mu;
          float rstd = rsqrtf(var + 1e-5f);
          float n2 = 0.0f;
          #pragma unroll
          for (int nh = 0; nh < 2; ++nh)
            #pragma unroll
            for (int ni = 0; ni < 2; ++ni) {
              float y = (v[mh][nh][mi][ni][r] - mu) * rstd * gg[nh][ni] + bb[nh][ni];
              v[mh][nh][mi][ni][r] = y;
              n2 += y * y;
            }
          for (int m = 1; m < 16; m <<= 1) n2 += __shfl_xor(n2, m, 64);
          n2loc[mh][mi][r] = n2;
        }
    #pragma unroll
    for (int mh = 0; mh < 2; ++mh)
      #pragma unroll
      for (int mi = 0; mi < MI; ++mi)
        #pragma unroll
        for (int r = 0; r < 4; ++r)
          if (fl == 0) {
            int lr = mh * 64 + wr * 32 + mi * 16 + fh * 4 + r;
            n2p[lr][wc] = n2loc[mh][mi][r];
          }
    __syncthreads();

    #pragma unroll
    for (int mh = 0; mh < 2; ++mh)
      #pragma unroll
      for (int mi = 0; mi < MI; ++mi)
        #pragma unroll
        for (int r = 0; r < 4; ++r) {
          int lr = mh * 64 + wr * 32 + mi * 16 + fh * 4 + r;
          float t = n2p[lr][0] + n2p[lr][1] + n2p[lr][2] + n2p[lr][3];
          float sc = 1.0f / fmaxf(sqrtf(t), 1e-12f);
          #pragma unroll
          for (int nh = 0; nh < 2; ++nh)
            #pragma unroll
            for (int ni = 0; ni < 2; ++ni) {
              int c = nh * 128 + wc * 32 + ni * 16 + fl;
              ((float*)Cv)[(mrow0 + lr) * NDIM + c] = v[mh][nh][mi][ni][r] * sc;
            }
        }
  } else {
    // ---- plain epilogue: bias (+relu/cast)
    #pragma unroll
    for (int mh = 0; mh < 2; ++mh)
      #pragma unroll
      for (int nh = 0; nh < 2; ++nh)
        #pragma unroll
        for (int ni = 0; ni < 2; ++ni) {
          int col = ncol0 + nh * 128 + wc * 32 + ni * 16 + fl;
          float bv = bias[col];
          #pragma unroll
          for (int mi = 0; mi < MI; ++mi)
            #pragma unroll
            for (int r = 0; r < 4; ++r) {
              long row = mrow0 + mh * BMH + wr * (BMH / 2) + mi * 16 + fh * 4 + r;
              float x = acc[mh][nh][mi][ni][r] + bv;
              if constexpr (RELU_OUT) {
                x = fmaxf(x, 0.0f);
                ((__bf16*)Cv)[row * NDIM + col] = (__bf16)x;
              } else {
                ((float*)Cv)[row * NDIM + col] = x;
              }
            }
        }
  }
}

// ---------------------------------------------------------------------------
// Per-row contrastive loss. One wave per row; 16-lane groups handle 4 negs
// at a time; negatives read as bf16 (halves L2 gather traffic).
// ---------------------------------------------------------------------------
__global__ __launch_bounds__(256)
void loss_kernel(const float* __restrict__ X, const __bf16* __restrict__ negb,
                 const int* __restrict__ nidx, float* __restrict__ partials) {
  __shared__ float lsum[4];
  int b    = blockIdx.x * 4 + (threadIdx.x >> 6);
  int lane = threadIdx.x & 63;
  int g = lane >> 4, lg = lane & 15;

  const float* arow = X + (size_t)b * PDIM;
  const float* prow = X + (size_t)(BATCH + b) * PDIM;

  float a16[16];
  #pragma unroll
  for (int j = 0; j < 4; ++j) {
    f32x4 av = *(const f32x4*)(arow + lg * 16 + j * 4);
    #pragma unroll
    for (int e = 0; e < 4; ++e) a16[j * 4 + e] = av[e];
  }

  float ps = 0.0f;
  #pragma unroll
  for (int j = 0; j < 4; ++j) {
    f32x4 p = *(const f32x4*)(prow + lg * 16 + j * 4);
    #pragma unroll
    for (int e = 0; e < 4; ++e) ps += a16[j * 4 + e] * p[e];
  }
  for (int m = 1; m < 16; m <<= 1) ps += __shfl_xor(ps, m, 64);
  float pos = ps * 2.0f;  // /TEMPERATURE

  float myneg = -3.0e38f;
  for (int k4 = 0; k4 < 16; ++k4) {
    int k = k4 * 4 + g;
    int idx = nidx[(size_t)b * KNEG + k];
    const __bf16* nrow = negb + (size_t)idx * PDIM;
    float sv = 0.0f;
    #pragma unroll
    for (int j = 0; j < 2; ++j) {
      bf16x8 nv = *(const bf16x8*)(nrow + lg * 16 + j * 8);
      #pragma unroll
      for (int e = 0; e < 8; ++e) sv += a16[j * 8 + e] * (float)nv[e];
    }
    for (int m = 1; m < 16; m <<= 1) sv += __shfl_xor(sv, m, 64);
    if (lg == k4) myneg = sv * 2.0f;
  }

  float mx = myneg;
  for (int m = 1; m < 64; m <<= 1) mx = fmaxf(mx, __shfl_xor(mx, m, 64));
  mx = fmaxf(mx, pos);
  float e = expf(myneg - mx);
  for (int m = 1; m < 64; m <<= 1) e += __shfl_xor(e, m, 64);
  float tot = e + expf(pos - mx);
  float lb = -(pos - mx - logf(tot));

  if (lane == 0) lsum[threadIdx.x >> 6] = lb;
  __syncthreads();
  if (threadIdx.x == 0)
    partials[blockIdx.x] = lsum[0] + lsum[1] + lsum[2] + lsum[3];
}

__global__ void finalize_kernel(const float* __restrict__ partials,
                                float* __restrict__ out) {
  __shared__ float ls[4];
  int tid = threadIdx.x;
  float s = 0.0f;
  for (int i = tid; i < 4096; i += 256) s += partials[i];
  for (int m = 1; m < 64; m <<= 1) s += __shfl_xor(s, m, 64);
  if ((tid & 63) == 0) ls[tid >> 6] = s;
  __syncthreads();
  if (tid == 0) out[0] = (ls[0] + ls[1] + ls[2] + ls[3]) * (1.0f / BATCH);
}

// ---------------------------------------------------------------------------
extern "C" void kernel_launch(void* const* d_in, const int* in_sizes, int n_in,
                              void* d_out, int out_size, void* d_ws, size_t ws_size,
                              hipStream_t stream) {
  const float* hidden   = (const float*)d_in[0];
  const float* positive = (const float*)d_in[1];
  const float* negbuf   = (const float*)d_in[2];
  const float* W1       = (const float*)d_in[3];
  const float* b1       = (const float*)d_in[4];
  const float* W2       = (const float*)d_in[5];
  const float* b2       = (const float*)d_in[6];
  const float* gamma    = (const float*)d_in[7];
  const float* beta     = (const float*)d_in[8];
  const int*   nidx     = (const int*)d_in[9];
  float* out = (float*)d_out;

  char* ws = (char*)d_ws;
  // Layout (~204 MiB; ws proven >= 206 MiB in rounds 2-6):
  //   Abf [32768][2048] bf16 @ 0          (134 MiB) -- dead after GEMM1
  //   Y1  [32768][1024] bf16 @ 134 MiB    ( 64 MiB)
  //   W1T                    @ 198 MiB    (  4 MiB)
  //   W2T                    @ 202 MiB    (0.5 MiB)
  //   negb [2000][256] bf16  @ 202.5 MiB  (  1 MiB)
  //   partials               @ 203.5 MiB  ( 16 KiB)
  //   X   [32768][256] f32   @ 0 (overlaps dead Abf, 32 MiB)
  const size_t OFF_Y1   = 134217728;
  const size_t OFF_W1T  = OFF_Y1 + 67108864;
  const size_t OFF_W2T  = OFF_W1T + 4194304;
  const size_t OFF_NEGB = OFF_W2T + 524288;
  const size_t OFF_PART = OFF_NEGB + 1048576;

  __bf16* Abf      = (__bf16*)(ws);
  __bf16* Y1       = (__bf16*)(ws + OFF_Y1);
  __bf16* W1T      = (__bf16*)(ws + OFF_W1T);
  __bf16* W2T      = (__bf16*)(ws + OFF_W2T);
  __bf16* negb     = (__bf16*)(ws + OFF_NEGB);
  float*  partials = (float*) (ws + OFF_PART);
  float*  X        = (float*) (ws);  // overlaps dead Abf

  transpose_cast_kernel<<<dim3(HHDIM / 32, HDIM / 32), dim3(32, 8), 0, stream>>>(
      W1, W1T, HDIM, HHDIM);
  transpose_cast_kernel<<<dim3(PDIM / 32, HHDIM / 32), dim3(32, 8), 0, stream>>>(
      W2, W2T, HHDIM, PDIM);

  // casts: anchors+positives -> Abf rows [0,16384)/[16384,32768); negbuf -> bf16
  const long n8 = (long)BATCH * HDIM / 8;
  cast_bf16_kernel<<<2048, 256, 0, stream>>>(hidden, Abf, n8);
  cast_bf16_kernel<<<2048, 256, 0, stream>>>(positive, Abf + (size_t)BATCH * HDIM, n8);
  cast_bf16_kernel<<<256, 256, 0, stream>>>(negbuf, negb, (long)NBUF * PDIM / 8);

  // GEMM1: Abf @ W1T^T + b1, relu -> Y1 (bf16). 256x256 tile. (r6-verified)
  gemm_8ph<HDIM, 128, HHDIM / 256, true, false, (M1 / 256) * (HHDIM / 256)>
      <<<(M1 / 256) * (HHDIM / 256), 512, 0, stream>>>(
          Abf, W1T, b1, nullptr, nullptr, Y1);

  // GEMM2: Y1 @ W2T^T + b2, fused LayerNorm + L2-normalize -> X (f32).
  // 128x256 tile, grid 256. (r7-verified)
  gemm_8ph<HHDIM, 64, PDIM / 256, false, true, (M1 / 128) * (PDIM / 256)>
      <<<(M1 / 128) * (PDIM / 256), 512, 0, stream>>>(
          Y1, W2T, b2, gamma, beta, X);

  loss_kernel<<<BATCH / 4, 256, 0, stream>>>(X, negb, nidx, partials);
  finalize_kernel<<<1, 256, 0, stream>>>(partials, out);
}